// Round 5
// baseline (661.761 us; speedup 1.0000x reference)
//
#include <hip/hip_runtime.h>

#define N_NODES 50000
#define N_EDGES 600000
#define N_GRAPHS 512
#define DIM 128
#define NLAYERS 4
#define NCLASSES 10
#define KPD 132   // padded LDS row stride in dwords (16B-aligned; even bank spread)

typedef __attribute__((ext_vector_type(8))) short short8;
typedef __attribute__((ext_vector_type(4))) float f32x4;

union Frag { short8 s; uint4 u; };

// ---- fp32 -> bf16 (RNE) helpers ----
__device__ inline unsigned short f2bf(float v) {
    union { float f; unsigned u; } c; c.f = v;
    unsigned u = c.u;
    u += 0x7FFFu + ((u >> 16) & 1u);
    return (unsigned short)(u >> 16);
}
__device__ inline float bf2f(unsigned short h) {
    union { float f; unsigned u; } c; c.u = ((unsigned)h) << 16;
    return c.f;
}

// ---------------------------------------------------------------------------
// CSR build step 1: in-degree histogram
// ---------------------------------------------------------------------------
__global__ __launch_bounds__(256) void hist_kernel(
    const int* __restrict__ dst, int* __restrict__ deg)
{
    int e = blockIdx.x * 256 + threadIdx.x;
    if (e >= N_EDGES) return;
    atomicAdd(&deg[dst[e]], 1);
}

// ---------------------------------------------------------------------------
// Hierarchical scan of deg -> rowptr/cursor
// ---------------------------------------------------------------------------
__global__ __launch_bounds__(256) void scan1_kernel(
    const int* __restrict__ deg, int* __restrict__ bsum)
{
    __shared__ int red[256];
    int t = threadIdx.x;
    int i4 = blockIdx.x * 256 + t;
    int s = 0;
    if (i4 < 12500) {
        int4 v = ((const int4*)deg)[i4];
        s = v.x + v.y + v.z + v.w;
    }
    red[t] = s;
    __syncthreads();
    for (int off = 128; off > 0; off >>= 1) {
        if (t < off) red[t] += red[t + off];
        __syncthreads();
    }
    if (t == 0) bsum[blockIdx.x] = red[0];
}

__global__ __launch_bounds__(64) void scan2_kernel(int* __restrict__ bsum)
{
    __shared__ int sh[64];
    int t = threadIdx.x;
    sh[t] = (t < 49) ? bsum[t] : 0;
    __syncthreads();
    if (t == 0) {
        int run = 0;
        for (int i = 0; i < 49; i++) { int v = sh[i]; sh[i] = run; run += v; }
    }
    __syncthreads();
    if (t < 49) bsum[t] = sh[t];
}

__global__ __launch_bounds__(256) void scan3_kernel(
    const int* __restrict__ deg, const int* __restrict__ bsum,
    int* __restrict__ rowptr, int* __restrict__ cursor)
{
    __shared__ int red[256];
    int t = threadIdx.x;
    int i4 = blockIdx.x * 256 + t;
    int4 v = {0, 0, 0, 0};
    if (i4 < 12500) v = ((const int4*)deg)[i4];
    int s = v.x + v.y + v.z + v.w;
    red[t] = s;
    __syncthreads();
    for (int off = 1; off < 256; off <<= 1) {
        int val = (t >= off) ? red[t - off] : 0;
        __syncthreads();
        red[t] += val;
        __syncthreads();
    }
    int run = bsum[blockIdx.x] + (t ? red[t - 1] : 0);
    if (i4 < 12500) {
        int4 rp;
        rp.x = run; run += v.x;
        rp.y = run; run += v.y;
        rp.z = run; run += v.z;
        rp.w = run; run += v.w;
        ((int4*)rowptr)[i4] = rp;
        ((int4*)cursor)[i4] = rp;
    }
    if (blockIdx.x == 0 && t == 0) rowptr[N_NODES] = N_EDGES;
}

// ---------------------------------------------------------------------------
// CSR build step 3: scatter edge src ids into their dst's row
// ---------------------------------------------------------------------------
__global__ __launch_bounds__(256) void fill_kernel(
    const int* __restrict__ src, const int* __restrict__ dst,
    int* __restrict__ cursor, int* __restrict__ csr)
{
    int e = blockIdx.x * 256 + threadIdx.x;
    if (e >= N_EDGES) return;
    int p = atomicAdd(&cursor[dst[e]], 1);
    csr[p] = src[e];
}

// ---------------------------------------------------------------------------
// Graph segment boundaries from the sorted batch vector
// ---------------------------------------------------------------------------
__global__ __launch_bounds__(256) void bounds_kernel(
    const int* __restrict__ batch, int* __restrict__ gstart)
{
    int n = blockIdx.x * 256 + threadIdx.x;
    if (n >= N_NODES) return;
    int b = batch[n];
    int bp = (n == 0) ? -1 : batch[n - 1];
    for (int g = bp + 1; g <= b; g++) gstart[g] = n;
    if (n == N_NODES - 1)
        for (int g = b + 1; g <= N_GRAPHS; g++) gstart[g] = N_NODES;
}

// ---------------------------------------------------------------------------
// Pre-swizzle W1/W2 (all layers) into MFMA B-fragment order, split hi/lo bf16.
// whi[ l*32768 + w01*16384 + ((ks*8+cg)*64+lane)*8 + j ]
//   = W[k = ks*32 + (lane>>4)*8 + j][n = cg*16 + (lane&15)]
// ---------------------------------------------------------------------------
__global__ __launch_bounds__(256) void wconv_kernel(
    const float* __restrict__ W1, const float* __restrict__ W2,
    unsigned short* __restrict__ whi, unsigned short* __restrict__ wlo)
{
    int idx = blockIdx.x * 256 + threadIdx.x;
    if (idx >= NLAYERS * 2 * 16384) return;
    int f   = idx & 16383;
    int w01 = (idx >> 14) & 1;
    int l   = idx >> 15;
    int j    = f & 7;
    int lane = (f >> 3) & 63;
    int cg   = (f >> 9) & 7;
    int ks   = f >> 12;
    int k = ks * 32 + (lane >> 4) * 8 + j;
    int n = cg * 16 + (lane & 15);
    const float* W = (w01 == 0 ? W1 : W2) + (size_t)l * 16384;
    float v = W[k * 128 + n];
    unsigned short hi = f2bf(v);
    unsigned short lo = f2bf(v - bf2f(hi));
    whi[idx] = hi;
    wlo[idx] = lo;
}

// ---------------------------------------------------------------------------
// MFMA MLP, high-ILP version: A-fragments straight from global (no staging),
// one packed-LDS buffer for the inter-GEMM transpose, batched B loads.
// Block: 32 nodes x 128 cols, 4 waves (wr = w&1 rows, wc = w>>1 cols).
// ---------------------------------------------------------------------------
__global__ __launch_bounds__(256, 3) void mlp_mfma_kernel(
    float* __restrict__ z,
    const unsigned short* __restrict__ whi, const unsigned short* __restrict__ wlo,
    const float* __restrict__ b1, const float* __restrict__ b2,
    float* __restrict__ stats)
{
    __shared__ unsigned int tpk[32 * KPD];   // packed (lo16<<16)|hi16, 16896 B

    const int t = threadIdx.x;
    const int lane = t & 63;
    const int w = t >> 6;
    const int wr = w & 1, wc = w >> 1;
    const int l15 = lane & 15, quad = lane >> 4;
    const int base = blockIdx.x * 32;

    // ---- A (GEMM1): direct global load, row clamped (invalid rows only feed
    //      invalid output rows -> never stored / never counted) ----
    int arow_n = base + 16 * wr + l15;
    if (arow_n >= N_NODES) arow_n = N_NODES - 1;
    const float* zrow = z + (size_t)arow_n * 128 + quad * 8;

    float4 af[4][2];
    #pragma unroll
    for (int ks = 0; ks < 4; ks++) {
        af[ks][0] = *((const float4*)(zrow + ks * 32));
        af[ks][1] = *((const float4*)(zrow + ks * 32 + 4));
    }

    Frag ahi[4], alo[4];
    #pragma unroll
    for (int ks = 0; ks < 4; ks++) {
        float vv[8] = {af[ks][0].x, af[ks][0].y, af[ks][0].z, af[ks][0].w,
                       af[ks][1].x, af[ks][1].y, af[ks][1].z, af[ks][1].w};
        unsigned hh[4], ll[4];
        #pragma unroll
        for (int p = 0; p < 4; p++) {
            unsigned short h0 = f2bf(vv[2 * p]);
            unsigned short h1 = f2bf(vv[2 * p + 1]);
            unsigned short l0 = f2bf(vv[2 * p] - bf2f(h0));
            unsigned short l1 = f2bf(vv[2 * p + 1] - bf2f(h1));
            hh[p] = (unsigned)h0 | ((unsigned)h1 << 16);
            ll[p] = (unsigned)l0 | ((unsigned)l1 << 16);
        }
        ahi[ks].u = (uint4){hh[0], hh[1], hh[2], hh[3]};
        alo[ks].u = (uint4){ll[0], ll[1], ll[2], ll[3]};
    }

    f32x4 acc[4];
    #pragma unroll
    for (int i = 0; i < 4; i++) acc[i] = (f32x4){0.f, 0.f, 0.f, 0.f};

    // ---- GEMM1: z0 @ W1 (batched B loads per ks, 12 MFMAs) ----
    #pragma unroll
    for (int ks = 0; ks < 4; ks++) {
        Frag bhi[4], blo[4];
        #pragma unroll
        for (int i = 0; i < 4; i++) {
            int cg = wc * 4 + i;
            size_t woff = (size_t)(((ks * 8 + cg) * 64 + lane) * 8);
            bhi[i].s = *((const short8*)&whi[woff]);
            blo[i].s = *((const short8*)&wlo[woff]);
        }
        #pragma unroll
        for (int i = 0; i < 4; i++) {
            acc[i] = __builtin_amdgcn_mfma_f32_16x16x32_bf16(alo[ks].s, bhi[i].s, acc[i], 0, 0, 0);
            acc[i] = __builtin_amdgcn_mfma_f32_16x16x32_bf16(ahi[ks].s, blo[i].s, acc[i], 0, 0, 0);
            acc[i] = __builtin_amdgcn_mfma_f32_16x16x32_bf16(ahi[ks].s, bhi[i].s, acc[i], 0, 0, 0);
        }
    }

    // ---- bias + relu -> t (packed hi|lo dwords in LDS, C->A transpose) ----
    #pragma unroll
    for (int i = 0; i < 4; i++) {
        int col = wc * 64 + i * 16 + l15;
        float bb = b1[col];
        #pragma unroll
        for (int r = 0; r < 4; r++) {
            int m = 16 * wr + quad * 4 + r;
            float v = fmaxf(acc[i][r] + bb, 0.f);
            unsigned short h = f2bf(v);
            unsigned short lo2 = f2bf(v - bf2f(h));
            tpk[m * KPD + col] = (unsigned)h | ((unsigned)lo2 << 16);
        }
        acc[i] = (f32x4){0.f, 0.f, 0.f, 0.f};
    }
    __syncthreads();

    // ---- A (GEMM2): b128 reads from packed LDS, unpack to hi/lo ----
    const int arowd = (16 * wr + l15) * KPD;
    Frag a2hi[4], a2lo[4];
    #pragma unroll
    for (int ks = 0; ks < 4; ks++) {
        uint4 u0 = *((uint4*)&tpk[arowd + ks * 32 + quad * 8]);
        uint4 u1 = *((uint4*)&tpk[arowd + ks * 32 + quad * 8 + 4]);
        a2hi[ks].u = (uint4){ (u0.x & 0xFFFFu) | (u0.y << 16),
                              (u0.z & 0xFFFFu) | (u0.w << 16),
                              (u1.x & 0xFFFFu) | (u1.y << 16),
                              (u1.z & 0xFFFFu) | (u1.w << 16) };
        a2lo[ks].u = (uint4){ (u0.x >> 16) | (u0.y & 0xFFFF0000u),
                              (u0.z >> 16) | (u0.w & 0xFFFF0000u),
                              (u1.x >> 16) | (u1.y & 0xFFFF0000u),
                              (u1.z >> 16) | (u1.w & 0xFFFF0000u) };
    }
    __syncthreads();   // all LDS reads done -> tpk reusable as scratch

    // ---- GEMM2: t @ W2 ----
    const unsigned short* w2hi = whi + 16384;
    const unsigned short* w2lo = wlo + 16384;
    #pragma unroll
    for (int ks = 0; ks < 4; ks++) {
        Frag bhi[4], blo[4];
        #pragma unroll
        for (int i = 0; i < 4; i++) {
            int cg = wc * 4 + i;
            size_t woff = (size_t)(((ks * 8 + cg) * 64 + lane) * 8);
            bhi[i].s = *((const short8*)&w2hi[woff]);
            blo[i].s = *((const short8*)&w2lo[woff]);
        }
        #pragma unroll
        for (int i = 0; i < 4; i++) {
            acc[i] = __builtin_amdgcn_mfma_f32_16x16x32_bf16(a2lo[ks].s, bhi[i].s, acc[i], 0, 0, 0);
            acc[i] = __builtin_amdgcn_mfma_f32_16x16x32_bf16(a2hi[ks].s, blo[i].s, acc[i], 0, 0, 0);
            acc[i] = __builtin_amdgcn_mfma_f32_16x16x32_bf16(a2hi[ks].s, bhi[i].s, acc[i], 0, 0, 0);
        }
    }

    // ---- bias + store z + BN partials ----
    float csum[4], csq[4];
    #pragma unroll
    for (int i = 0; i < 4; i++) {
        int col = wc * 64 + i * 16 + l15;
        float bb = b2[col];
        float s = 0.f, q2 = 0.f;
        #pragma unroll
        for (int r = 0; r < 4; r++) {
            int m = 16 * wr + quad * 4 + r;
            int n = base + m;
            float v = acc[i][r] + bb;
            if (n < N_NODES) {
                z[(size_t)n * 128 + col] = v;
                s += v; q2 += v * v;
            }
        }
        csum[i] = s; csq[i] = q2;
    }

    // ---- block stats reduction (tpk as float scratch: 2048 of 4224 dwords) ----
    float* sums = (float*)tpk;
    float* sqs  = (float*)tpk + 1024;
    #pragma unroll
    for (int i = 0; i < 4; i++) {
        sums[(w * 4 + i) * 64 + lane] = csum[i];
        sqs [(w * 4 + i) * 64 + lane] = csq[i];
    }
    __syncthreads();
    if (t < 128) {
        int c = t;
        int wcc = c >> 6, ci = (c >> 4) & 3, cl = c & 15;
        float s = 0.f, q2 = 0.f;
        #pragma unroll
        for (int wrr = 0; wrr < 2; wrr++) {
            int ww = wcc * 2 + wrr;
            #pragma unroll
            for (int u = 0; u < 4; u++) {
                int ln = cl + u * 16;
                s  += sums[(ww * 4 + ci) * 64 + ln];
                q2 += sqs [(ww * 4 + ci) * 64 + ln];
            }
        }
        unsafeAtomicAdd(&stats[c], s);
        unsafeAtomicAdd(&stats[128 + c], q2);
    }
}

// ---------------------------------------------------------------------------
// Pull-aggregation + GIN self term
// ---------------------------------------------------------------------------
__global__ __launch_bounds__(256) void gather_kernel(
    const float* __restrict__ h, const int* __restrict__ rowptr,
    const int* __restrict__ csr, const float* __restrict__ epsP,
    float* __restrict__ z)
{
    int t = threadIdx.x;
    int n = blockIdx.x * 8 + (t >> 5);
    int q = t & 31;
    if (n >= N_NODES) return;
    int beg = rowptr[n], end = rowptr[n + 1];
    float e1 = 1.0f + epsP[0];
    float4 acc = ((const float4*)h)[(size_t)n * 32 + q];
    acc.x *= e1; acc.y *= e1; acc.z *= e1; acc.w *= e1;
    int e = beg;
    for (; e + 1 < end; e += 2) {
        int s0 = csr[e], s1 = csr[e + 1];
        float4 v0 = ((const float4*)h)[(size_t)s0 * 32 + q];
        float4 v1 = ((const float4*)h)[(size_t)s1 * 32 + q];
        acc.x += v0.x + v1.x; acc.y += v0.y + v1.y;
        acc.z += v0.z + v1.z; acc.w += v0.w + v1.w;
    }
    if (e < end) {
        int s0 = csr[e];
        float4 v0 = ((const float4*)h)[(size_t)s0 * 32 + q];
        acc.x += v0.x; acc.y += v0.y; acc.z += v0.z; acc.w += v0.w;
    }
    ((float4*)z)[(size_t)n * 32 + q] = acc;
}

// ---------------------------------------------------------------------------
// BN apply + ReLU + write h + pool: one block per graph, zero atomics
// ---------------------------------------------------------------------------
__global__ __launch_bounds__(256) void bnpool_kernel(
    const float* __restrict__ z, const float* __restrict__ stats,
    const float* __restrict__ gamma, const float* __restrict__ beta,
    const int* __restrict__ gstart, float* __restrict__ hout,
    float* __restrict__ pools, int layer)
{
    __shared__ float red[8][128];
    const int g = blockIdx.x;
    const int t = threadIdx.x;
    const int q = t & 31, r = t >> 5;
    const int beg = gstart[g], end = gstart[g + 1];

    float4 s  = ((const float4*)stats)[q];
    float4 sq = ((const float4*)stats)[32 + q];
    float4 gm = ((const float4*)gamma)[q];
    float4 bt = ((const float4*)beta)[q];
    const float invN = 1.0f / (float)N_NODES;
    float m, vr;
    float4 scl, sh;
    m = s.x * invN; vr = sq.x * invN - m * m; scl.x = gm.x * rsqrtf(vr + 1e-5f); sh.x = bt.x - m * scl.x;
    m = s.y * invN; vr = sq.y * invN - m * m; scl.y = gm.y * rsqrtf(vr + 1e-5f); sh.y = bt.y - m * scl.y;
    m = s.z * invN; vr = sq.z * invN - m * m; scl.z = gm.z * rsqrtf(vr + 1e-5f); sh.z = bt.z - m * scl.z;
    m = s.w * invN; vr = sq.w * invN - m * m; scl.w = gm.w * rsqrtf(vr + 1e-5f); sh.w = bt.w - m * scl.w;

    float4 acc = {0.f, 0.f, 0.f, 0.f};
    for (int n = beg + r; n < end; n += 8) {
        float4 zv = ((const float4*)z)[(size_t)n * 32 + q];
        float4 hv;
        hv.x = fmaxf(zv.x * scl.x + sh.x, 0.f);
        hv.y = fmaxf(zv.y * scl.y + sh.y, 0.f);
        hv.z = fmaxf(zv.z * scl.z + sh.z, 0.f);
        hv.w = fmaxf(zv.w * scl.w + sh.w, 0.f);
        ((float4*)hout)[(size_t)n * 32 + q] = hv;
        acc.x += hv.x; acc.y += hv.y; acc.z += hv.z; acc.w += hv.w;
    }
    red[r][q * 4 + 0] = acc.x;
    red[r][q * 4 + 1] = acc.y;
    red[r][q * 4 + 2] = acc.z;
    red[r][q * 4 + 3] = acc.w;
    __syncthreads();
    if (t < 128) {
        float sm = 0.f;
        #pragma unroll
        for (int rr = 0; rr < 8; rr++) sm += red[rr][t];
        pools[(size_t)g * (DIM * NLAYERS) + (size_t)layer * DIM + t] = sm;
    }
}

// ---------------------------------------------------------------------------
// Final linear head
// ---------------------------------------------------------------------------
__global__ __launch_bounds__(256) void final_kernel(
    const float* __restrict__ pools, const float* __restrict__ Wlin,
    const float* __restrict__ blin, float* __restrict__ out)
{
    int idx = blockIdx.x * 256 + threadIdx.x;
    if (idx >= N_GRAPHS * NCLASSES) return;
    int g = idx / NCLASSES, o = idx % NCLASSES;
    const float* xr = pools + (size_t)g * (DIM * NLAYERS);
    float acc = blin[o];
    for (int k = 0; k < DIM * NLAYERS; k++)
        acc += xr[k] * Wlin[(size_t)k * NCLASSES + o];
    out[idx] = acc;
}

// ---------------------------------------------------------------------------
extern "C" void kernel_launch(void* const* d_in, const int* in_sizes, int n_in,
                              void* d_out, int out_size, void* d_ws, size_t ws_size,
                              hipStream_t stream)
{
    const float* x     = (const float*)d_in[0];
    const int*   src   = (const int*)d_in[1];
    const int*   dst   = ((const int*)d_in[1]) + N_EDGES;
    const int*   batch = (const int*)d_in[2];
    const float* W1    = (const float*)d_in[3];
    const float* b1    = (const float*)d_in[4];
    const float* W2    = (const float*)d_in[5];
    const float* b2    = (const float*)d_in[6];
    const float* eps   = (const float*)d_in[7];
    const float* gamma = (const float*)d_in[8];
    const float* beta  = (const float*)d_in[9];
    const float* Wlin  = (const float*)d_in[10];
    const float* blin  = (const float*)d_in[11];
    float* out = (float*)d_out;

    char* ws = (char*)d_ws;
    const size_t FEAT = (size_t)N_NODES * DIM * sizeof(float);       // 25.6 MB
    size_t off = 0;
    float* buf_h  = (float*)(ws + off); off += FEAT;
    float* buf_z  = (float*)(ws + off); off += FEAT;
    float* pools  = (float*)(ws + off); off += (size_t)N_GRAPHS * DIM * NLAYERS * sizeof(float);
    float* stats  = (float*)(ws + off); off += (size_t)NLAYERS * 256 * sizeof(float);
    int*   deg    = (int*)(ws + off);   off += (size_t)N_NODES * sizeof(int);      // also "cursor"
    int*   rowptr = (int*)(ws + off);   off += (size_t)(N_NODES + 1) * sizeof(int) + 12;
    int*   csr    = (int*)(ws + off);   off += (size_t)N_EDGES * sizeof(int);
    int*   gstart = (int*)(ws + off);   off += 2064;     // 513 ints, padded
    int*   bsum   = (int*)(ws + off);   off += 208;      // 49 ints, padded
    unsigned short* whi = (unsigned short*)(ws + off); off += (size_t)NLAYERS * 2 * 16384 * 2;
    unsigned short* wlo = (unsigned short*)(ws + off); off += (size_t)NLAYERS * 2 * 16384 * 2;

    hipMemsetAsync(stats, 0, (size_t)NLAYERS * 256 * sizeof(float), stream);
    hipMemsetAsync(deg, 0, (size_t)N_NODES * sizeof(int), stream);

    // ---- once per call: CSR, graph bounds, weight pre-swizzle ----
    hist_kernel<<<(N_EDGES + 255) / 256, 256, 0, stream>>>(dst, deg);
    scan1_kernel<<<49, 256, 0, stream>>>(deg, bsum);
    scan2_kernel<<<1, 64, 0, stream>>>(bsum);
    scan3_kernel<<<49, 256, 0, stream>>>(deg, bsum, rowptr, deg /*cursor*/);
    fill_kernel<<<(N_EDGES + 255) / 256, 256, 0, stream>>>(src, dst, deg, csr);
    bounds_kernel<<<(N_NODES + 255) / 256, 256, 0, stream>>>(batch, gstart);
    wconv_kernel<<<(NLAYERS * 2 * 16384 + 255) / 256, 256, 0, stream>>>(W1, W2, whi, wlo);

    for (int l = 0; l < NLAYERS; l++) {
        const float* hin = (l == 0) ? x : buf_h;
        gather_kernel<<<(N_NODES + 7) / 8, 256, 0, stream>>>(
            hin, rowptr, csr, eps + l, buf_z);
        mlp_mfma_kernel<<<(N_NODES + 31) / 32, 256, 0, stream>>>(
            buf_z,
            whi + (size_t)l * 32768, wlo + (size_t)l * 32768,
            b1 + (size_t)l * DIM, b2 + (size_t)l * DIM,
            stats + (size_t)l * 256);
        bnpool_kernel<<<N_GRAPHS, 256, 0, stream>>>(
            buf_z, stats + (size_t)l * 256,
            gamma + (size_t)l * DIM, beta + (size_t)l * DIM,
            gstart, buf_h, pools, l);
    }
    final_kernel<<<(N_GRAPHS * NCLASSES + 255) / 256, 256, 0, stream>>>(
        pools, Wlin, blin, out);
}

// Round 6
// 576.053 us; speedup vs baseline: 1.1488x; 1.1488x over previous
//
#include <hip/hip_runtime.h>

#define N_NODES 50000
#define N_EDGES 600000
#define N_GRAPHS 512
#define DIM 128
#define NLAYERS 4
#define NCLASSES 10
#define KPD 132   // padded LDS row stride in dwords

typedef __attribute__((ext_vector_type(8))) short short8;
typedef __attribute__((ext_vector_type(4))) float f32x4;

union Frag { short8 s; uint4 u; };

// ---- fp32 -> bf16 (RNE) helpers ----
__device__ inline unsigned short f2bf(float v) {
    union { float f; unsigned u; } c; c.f = v;
    unsigned u = c.u;
    u += 0x7FFFu + ((u >> 16) & 1u);
    return (unsigned short)(u >> 16);
}
__device__ inline float bf2f(unsigned short h) {
    union { float f; unsigned u; } c; c.u = ((unsigned)h) << 16;
    return c.f;
}
// pack 8 floats -> hi frag + lo frag (2 bf16 per dword)
__device__ inline void cvt8(const float4& x, const float4& y, uint4& hi, uint4& lo) {
    float vv[8] = {x.x, x.y, x.z, x.w, y.x, y.y, y.z, y.w};
    unsigned hh[4], ll[4];
    #pragma unroll
    for (int p = 0; p < 4; p++) {
        unsigned short h0 = f2bf(vv[2 * p]);
        unsigned short h1 = f2bf(vv[2 * p + 1]);
        unsigned short l0 = f2bf(vv[2 * p] - bf2f(h0));
        unsigned short l1 = f2bf(vv[2 * p + 1] - bf2f(h1));
        hh[p] = (unsigned)h0 | ((unsigned)h1 << 16);
        ll[p] = (unsigned)l0 | ((unsigned)l1 << 16);
    }
    hi = (uint4){hh[0], hh[1], hh[2], hh[3]};
    lo = (uint4){ll[0], ll[1], ll[2], ll[3]};
}

// ---------------------------------------------------------------------------
// CSR build
// ---------------------------------------------------------------------------
__global__ __launch_bounds__(256) void hist_kernel(
    const int* __restrict__ dst, int* __restrict__ deg)
{
    int e = blockIdx.x * 256 + threadIdx.x;
    if (e >= N_EDGES) return;
    atomicAdd(&deg[dst[e]], 1);
}

__global__ __launch_bounds__(256) void scan1_kernel(
    const int* __restrict__ deg, int* __restrict__ bsum)
{
    __shared__ int red[256];
    int t = threadIdx.x;
    int i4 = blockIdx.x * 256 + t;
    int s = 0;
    if (i4 < 12500) {
        int4 v = ((const int4*)deg)[i4];
        s = v.x + v.y + v.z + v.w;
    }
    red[t] = s;
    __syncthreads();
    for (int off = 128; off > 0; off >>= 1) {
        if (t < off) red[t] += red[t + off];
        __syncthreads();
    }
    if (t == 0) bsum[blockIdx.x] = red[0];
}

__global__ __launch_bounds__(64) void scan2_kernel(int* __restrict__ bsum)
{
    __shared__ int sh[64];
    int t = threadIdx.x;
    sh[t] = (t < 49) ? bsum[t] : 0;
    __syncthreads();
    if (t == 0) {
        int run = 0;
        for (int i = 0; i < 49; i++) { int v = sh[i]; sh[i] = run; run += v; }
    }
    __syncthreads();
    if (t < 49) bsum[t] = sh[t];
}

__global__ __launch_bounds__(256) void scan3_kernel(
    const int* __restrict__ deg, const int* __restrict__ bsum,
    int* __restrict__ rowptr, int* __restrict__ cursor)
{
    __shared__ int red[256];
    int t = threadIdx.x;
    int i4 = blockIdx.x * 256 + t;
    int4 v = {0, 0, 0, 0};
    if (i4 < 12500) v = ((const int4*)deg)[i4];
    int s = v.x + v.y + v.z + v.w;
    red[t] = s;
    __syncthreads();
    for (int off = 1; off < 256; off <<= 1) {
        int val = (t >= off) ? red[t - off] : 0;
        __syncthreads();
        red[t] += val;
        __syncthreads();
    }
    int run = bsum[blockIdx.x] + (t ? red[t - 1] : 0);
    if (i4 < 12500) {
        int4 rp;
        rp.x = run; run += v.x;
        rp.y = run; run += v.y;
        rp.z = run; run += v.z;
        rp.w = run; run += v.w;
        ((int4*)rowptr)[i4] = rp;
        ((int4*)cursor)[i4] = rp;
    }
    if (blockIdx.x == 0 && t == 0) rowptr[N_NODES] = N_EDGES;
}

__global__ __launch_bounds__(256) void fill_kernel(
    const int* __restrict__ src, const int* __restrict__ dst,
    int* __restrict__ cursor, int* __restrict__ csr)
{
    int e = blockIdx.x * 256 + threadIdx.x;
    if (e >= N_EDGES) return;
    int p = atomicAdd(&cursor[dst[e]], 1);
    csr[p] = src[e];
}

__global__ __launch_bounds__(256) void bounds_kernel(
    const int* __restrict__ batch, int* __restrict__ gstart)
{
    int n = blockIdx.x * 256 + threadIdx.x;
    if (n >= N_NODES) return;
    int b = batch[n];
    int bp = (n == 0) ? -1 : batch[n - 1];
    for (int g = bp + 1; g <= b; g++) gstart[g] = n;
    if (n == N_NODES - 1)
        for (int g = b + 1; g <= N_GRAPHS; g++) gstart[g] = N_NODES;
}

// ---------------------------------------------------------------------------
// Pre-swizzle W1/W2 into MFMA B-fragment order, bf16 hi only.
// whi[ l*32768 + w01*16384 + ((ks*8+cg)*64+lane)*8 + j ]
//   = bf16( W[k = ks*32 + (lane>>4)*8 + j][n = cg*16 + (lane&15)] )
// ---------------------------------------------------------------------------
__global__ __launch_bounds__(256) void wconv_kernel(
    const float* __restrict__ W1, const float* __restrict__ W2,
    unsigned short* __restrict__ whi)
{
    int idx = blockIdx.x * 256 + threadIdx.x;
    if (idx >= NLAYERS * 2 * 16384) return;
    int f   = idx & 16383;
    int w01 = (idx >> 14) & 1;
    int l   = idx >> 15;
    int j    = f & 7;
    int lane = (f >> 3) & 63;
    int cg   = (f >> 9) & 7;
    int ks   = f >> 12;
    int k = ks * 32 + (lane >> 4) * 8 + j;
    int n = cg * 16 + (lane & 15);
    const float* W = (w01 == 0 ? W1 : W2) + (size_t)l * 16384;
    whi[idx] = f2bf(W[k * 128 + n]);
}

// ---------------------------------------------------------------------------
// MFMA MLP, M=64 tile, B hi-only, A hi/lo split.
// 4 waves: wr=w&1 -> rows 32*wr..+32 (2 strips of 16), wc=w>>1 -> cols 64*wc.
// Per ks-half (2 ks): 8 B loads + 8 A loads all issued into live regs, then
// 32 MFMAs (2 ks x 2 strips x 4 cg x {alo,ahi}).
// ---------------------------------------------------------------------------
__global__ __launch_bounds__(256, 2) void mlp_mfma_kernel(
    float* __restrict__ z,
    const unsigned short* __restrict__ whi,
    const float* __restrict__ b1, const float* __restrict__ b2,
    float* __restrict__ stats)
{
    __shared__ unsigned int tpk[64 * KPD];   // packed (lo16<<16)|hi16, 33792 B

    const int t = threadIdx.x;
    const int lane = t & 63;
    const int w = t >> 6;
    const int wr = w & 1, wc = w >> 1;
    const int l15 = lane & 15, quad = lane >> 4;
    const int base = blockIdx.x * 64;

    // A row pointers (2 strips), clamped
    int n0 = base + 32 * wr + l15;
    int n1 = n0 + 16;
    if (n0 >= N_NODES) n0 = N_NODES - 1;
    if (n1 >= N_NODES) n1 = N_NODES - 1;
    const float* r0 = z + (size_t)n0 * 128 + quad * 8;
    const float* r1 = z + (size_t)n1 * 128 + quad * 8;

    f32x4 acc[2][4];
    #pragma unroll
    for (int s = 0; s < 2; s++)
        #pragma unroll
        for (int i = 0; i < 4; i++) acc[s][i] = (f32x4){0.f, 0.f, 0.f, 0.f};

    // ================= GEMM1: z0 @ W1 =================
    #pragma unroll
    for (int kh = 0; kh < 2; kh++) {
        // ---- issue all 8 B loads + 8 A loads (independent, live together) ----
        Frag bf[2][4];
        float4 a0r[2][2], a1r[2][2];
        #pragma unroll
        for (int kk = 0; kk < 2; kk++) {
            int ks = kh * 2 + kk;
            #pragma unroll
            for (int i = 0; i < 4; i++) {
                size_t woff = (size_t)(((ks * 8 + wc * 4 + i) * 64 + lane) * 8);
                bf[kk][i].s = *((const short8*)&whi[woff]);
            }
            a0r[kk][0] = *((const float4*)(r0 + ks * 32));
            a0r[kk][1] = *((const float4*)(r0 + ks * 32 + 4));
            a1r[kk][0] = *((const float4*)(r1 + ks * 32));
            a1r[kk][1] = *((const float4*)(r1 + ks * 32 + 4));
        }
        // ---- convert + MFMA ----
        #pragma unroll
        for (int kk = 0; kk < 2; kk++) {
            uint4 h0, l0, h1, l1;
            cvt8(a0r[kk][0], a0r[kk][1], h0, l0);
            cvt8(a1r[kk][0], a1r[kk][1], h1, l1);
            Frag ah0, al0, ah1, al1;
            ah0.u = h0; al0.u = l0; ah1.u = h1; al1.u = l1;
            #pragma unroll
            for (int i = 0; i < 4; i++) {
                acc[0][i] = __builtin_amdgcn_mfma_f32_16x16x32_bf16(al0.s, bf[kk][i].s, acc[0][i], 0, 0, 0);
                acc[0][i] = __builtin_amdgcn_mfma_f32_16x16x32_bf16(ah0.s, bf[kk][i].s, acc[0][i], 0, 0, 0);
                acc[1][i] = __builtin_amdgcn_mfma_f32_16x16x32_bf16(al1.s, bf[kk][i].s, acc[1][i], 0, 0, 0);
                acc[1][i] = __builtin_amdgcn_mfma_f32_16x16x32_bf16(ah1.s, bf[kk][i].s, acc[1][i], 0, 0, 0);
            }
        }
    }

    // ---- bias + relu -> packed t in LDS (C->A transpose) ----
    #pragma unroll
    for (int i = 0; i < 4; i++) {
        int col = wc * 64 + i * 16 + l15;
        float bb = b1[col];
        #pragma unroll
        for (int s = 0; s < 2; s++) {
            #pragma unroll
            for (int r = 0; r < 4; r++) {
                int m = 32 * wr + 16 * s + quad * 4 + r;
                float v = fmaxf(acc[s][i][r] + bb, 0.f);
                unsigned short h = f2bf(v);
                unsigned short lo2 = f2bf(v - bf2f(h));
                tpk[m * KPD + col] = (unsigned)h | ((unsigned)lo2 << 16);
            }
            acc[s][i] = (f32x4){0.f, 0.f, 0.f, 0.f};
        }
    }
    __syncthreads();

    // ================= GEMM2: t @ W2 =================
    const unsigned short* w2 = whi + 16384;
    const int arowd0 = (32 * wr + l15) * KPD;
    const int arowd1 = arowd0 + 16 * KPD;
    #pragma unroll
    for (int kh = 0; kh < 2; kh++) {
        Frag bf[2][4];
        uint4 u00[2], u01[2], u10[2], u11[2];
        #pragma unroll
        for (int kk = 0; kk < 2; kk++) {
            int ks = kh * 2 + kk;
            #pragma unroll
            for (int i = 0; i < 4; i++) {
                size_t woff = (size_t)(((ks * 8 + wc * 4 + i) * 64 + lane) * 8);
                bf[kk][i].s = *((const short8*)&w2[woff]);
            }
            int kd = ks * 32 + quad * 8;
            u00[kk] = *((uint4*)&tpk[arowd0 + kd]);
            u01[kk] = *((uint4*)&tpk[arowd0 + kd + 4]);
            u10[kk] = *((uint4*)&tpk[arowd1 + kd]);
            u11[kk] = *((uint4*)&tpk[arowd1 + kd + 4]);
        }
        #pragma unroll
        for (int kk = 0; kk < 2; kk++) {
            Frag ah0, al0, ah1, al1;
            ah0.u = (uint4){ (u00[kk].x & 0xFFFFu) | (u00[kk].y << 16),
                             (u00[kk].z & 0xFFFFu) | (u00[kk].w << 16),
                             (u01[kk].x & 0xFFFFu) | (u01[kk].y << 16),
                             (u01[kk].z & 0xFFFFu) | (u01[kk].w << 16) };
            al0.u = (uint4){ (u00[kk].x >> 16) | (u00[kk].y & 0xFFFF0000u),
                             (u00[kk].z >> 16) | (u00[kk].w & 0xFFFF0000u),
                             (u01[kk].x >> 16) | (u01[kk].y & 0xFFFF0000u),
                             (u01[kk].z >> 16) | (u01[kk].w & 0xFFFF0000u) };
            ah1.u = (uint4){ (u10[kk].x & 0xFFFFu) | (u10[kk].y << 16),
                             (u10[kk].z & 0xFFFFu) | (u10[kk].w << 16),
                             (u11[kk].x & 0xFFFFu) | (u11[kk].y << 16),
                             (u11[kk].z & 0xFFFFu) | (u11[kk].w << 16) };
            al1.u = (uint4){ (u10[kk].x >> 16) | (u10[kk].y & 0xFFFF0000u),
                             (u10[kk].z >> 16) | (u10[kk].w & 0xFFFF0000u),
                             (u11[kk].x >> 16) | (u11[kk].y & 0xFFFF0000u),
                             (u11[kk].z >> 16) | (u11[kk].w & 0xFFFF0000u) };
            #pragma unroll
            for (int i = 0; i < 4; i++) {
                acc[0][i] = __builtin_amdgcn_mfma_f32_16x16x32_bf16(al0.s, bf[kk][i].s, acc[0][i], 0, 0, 0);
                acc[0][i] = __builtin_amdgcn_mfma_f32_16x16x32_bf16(ah0.s, bf[kk][i].s, acc[0][i], 0, 0, 0);
                acc[1][i] = __builtin_amdgcn_mfma_f32_16x16x32_bf16(al1.s, bf[kk][i].s, acc[1][i], 0, 0, 0);
                acc[1][i] = __builtin_amdgcn_mfma_f32_16x16x32_bf16(ah1.s, bf[kk][i].s, acc[1][i], 0, 0, 0);
            }
        }
    }
    __syncthreads();   // LDS reads done -> tpk reusable as scratch

    // ---- bias + store z + BN partials ----
    float colsum[4], colsq[4];
    #pragma unroll
    for (int i = 0; i < 4; i++) {
        int col = wc * 64 + i * 16 + l15;
        float bb = b2[col];
        float su = 0.f, q2 = 0.f;
        #pragma unroll
        for (int s = 0; s < 2; s++) {
            #pragma unroll
            for (int r = 0; r < 4; r++) {
                int n = base + 32 * wr + 16 * s + quad * 4 + r;
                float v = acc[s][i][r] + bb;
                if (n < N_NODES) {
                    z[(size_t)n * 128 + col] = v;
                    su += v; q2 += v * v;
                }
            }
        }
        colsum[i] = su; colsq[i] = q2;
    }

    // ---- block stats reduction (tpk as float scratch) ----
    float* sums = (float*)tpk;
    float* sqs  = (float*)tpk + 1024;
    #pragma unroll
    for (int i = 0; i < 4; i++) {
        sums[(w * 4 + i) * 64 + lane] = colsum[i];
        sqs [(w * 4 + i) * 64 + lane] = colsq[i];
    }
    __syncthreads();
    if (t < 128) {
        int c = t;
        int wcc = c >> 6, ci = (c >> 4) & 3, cl = c & 15;
        float s = 0.f, q2 = 0.f;
        #pragma unroll
        for (int wrr = 0; wrr < 2; wrr++) {
            int ww = wcc * 2 + wrr;
            #pragma unroll
            for (int u = 0; u < 4; u++) {
                int ln = cl + u * 16;
                s  += sums[(ww * 4 + ci) * 64 + ln];
                q2 += sqs [(ww * 4 + ci) * 64 + ln];
            }
        }
        unsafeAtomicAdd(&stats[c], s);
        unsafeAtomicAdd(&stats[128 + c], q2);
    }
}

// ---------------------------------------------------------------------------
// Pull-aggregation + GIN self term
// ---------------------------------------------------------------------------
__global__ __launch_bounds__(256) void gather_kernel(
    const float* __restrict__ h, const int* __restrict__ rowptr,
    const int* __restrict__ csr, const float* __restrict__ epsP,
    float* __restrict__ z)
{
    int t = threadIdx.x;
    int n = blockIdx.x * 8 + (t >> 5);
    int q = t & 31;
    if (n >= N_NODES) return;
    int beg = rowptr[n], end = rowptr[n + 1];
    float e1 = 1.0f + epsP[0];
    float4 acc = ((const float4*)h)[(size_t)n * 32 + q];
    acc.x *= e1; acc.y *= e1; acc.z *= e1; acc.w *= e1;
    int e = beg;
    for (; e + 1 < end; e += 2) {
        int s0 = csr[e], s1 = csr[e + 1];
        float4 v0 = ((const float4*)h)[(size_t)s0 * 32 + q];
        float4 v1 = ((const float4*)h)[(size_t)s1 * 32 + q];
        acc.x += v0.x + v1.x; acc.y += v0.y + v1.y;
        acc.z += v0.z + v1.z; acc.w += v0.w + v1.w;
    }
    if (e < end) {
        int s0 = csr[e];
        float4 v0 = ((const float4*)h)[(size_t)s0 * 32 + q];
        acc.x += v0.x; acc.y += v0.y; acc.z += v0.z; acc.w += v0.w;
    }
    ((float4*)z)[(size_t)n * 32 + q] = acc;
}

// ---------------------------------------------------------------------------
// BN apply + ReLU + write h + pool: one block per graph, zero atomics
// ---------------------------------------------------------------------------
__global__ __launch_bounds__(256) void bnpool_kernel(
    const float* __restrict__ z, const float* __restrict__ stats,
    const float* __restrict__ gamma, const float* __restrict__ beta,
    const int* __restrict__ gstart, float* __restrict__ hout,
    float* __restrict__ pools, int layer)
{
    __shared__ float red[8][128];
    const int g = blockIdx.x;
    const int t = threadIdx.x;
    const int q = t & 31, r = t >> 5;
    const int beg = gstart[g], end = gstart[g + 1];

    float4 s  = ((const float4*)stats)[q];
    float4 sq = ((const float4*)stats)[32 + q];
    float4 gm = ((const float4*)gamma)[q];
    float4 bt = ((const float4*)beta)[q];
    const float invN = 1.0f / (float)N_NODES;
    float m, vr;
    float4 scl, sh;
    m = s.x * invN; vr = sq.x * invN - m * m; scl.x = gm.x * rsqrtf(vr + 1e-5f); sh.x = bt.x - m * scl.x;
    m = s.y * invN; vr = sq.y * invN - m * m; scl.y = gm.y * rsqrtf(vr + 1e-5f); sh.y = bt.y - m * scl.y;
    m = s.z * invN; vr = sq.z * invN - m * m; scl.z = gm.z * rsqrtf(vr + 1e-5f); sh.z = bt.z - m * scl.z;
    m = s.w * invN; vr = sq.w * invN - m * m; scl.w = gm.w * rsqrtf(vr + 1e-5f); sh.w = bt.w - m * scl.w;

    float4 acc = {0.f, 0.f, 0.f, 0.f};
    for (int n = beg + r; n < end; n += 8) {
        float4 zv = ((const float4*)z)[(size_t)n * 32 + q];
        float4 hv;
        hv.x = fmaxf(zv.x * scl.x + sh.x, 0.f);
        hv.y = fmaxf(zv.y * scl.y + sh.y, 0.f);
        hv.z = fmaxf(zv.z * scl.z + sh.z, 0.f);
        hv.w = fmaxf(zv.w * scl.w + sh.w, 0.f);
        ((float4*)hout)[(size_t)n * 32 + q] = hv;
        acc.x += hv.x; acc.y += hv.y; acc.z += hv.z; acc.w += hv.w;
    }
    red[r][q * 4 + 0] = acc.x;
    red[r][q * 4 + 1] = acc.y;
    red[r][q * 4 + 2] = acc.z;
    red[r][q * 4 + 3] = acc.w;
    __syncthreads();
    if (t < 128) {
        float sm = 0.f;
        #pragma unroll
        for (int rr = 0; rr < 8; rr++) sm += red[rr][t];
        pools[(size_t)g * (DIM * NLAYERS) + (size_t)layer * DIM + t] = sm;
    }
}

// ---------------------------------------------------------------------------
// Final linear head
// ---------------------------------------------------------------------------
__global__ __launch_bounds__(256) void final_kernel(
    const float* __restrict__ pools, const float* __restrict__ Wlin,
    const float* __restrict__ blin, float* __restrict__ out)
{
    int idx = blockIdx.x * 256 + threadIdx.x;
    if (idx >= N_GRAPHS * NCLASSES) return;
    int g = idx / NCLASSES, o = idx % NCLASSES;
    const float* xr = pools + (size_t)g * (DIM * NLAYERS);
    float acc = blin[o];
    for (int k = 0; k < DIM * NLAYERS; k++)
        acc += xr[k] * Wlin[(size_t)k * NCLASSES + o];
    out[idx] = acc;
}

// ---------------------------------------------------------------------------
extern "C" void kernel_launch(void* const* d_in, const int* in_sizes, int n_in,
                              void* d_out, int out_size, void* d_ws, size_t ws_size,
                              hipStream_t stream)
{
    const float* x     = (const float*)d_in[0];
    const int*   src   = (const int*)d_in[1];
    const int*   dst   = ((const int*)d_in[1]) + N_EDGES;
    const int*   batch = (const int*)d_in[2];
    const float* W1    = (const float*)d_in[3];
    const float* b1    = (const float*)d_in[4];
    const float* W2    = (const float*)d_in[5];
    const float* b2    = (const float*)d_in[6];
    const float* eps   = (const float*)d_in[7];
    const float* gamma = (const float*)d_in[8];
    const float* beta  = (const float*)d_in[9];
    const float* Wlin  = (const float*)d_in[10];
    const float* blin  = (const float*)d_in[11];
    float* out = (float*)d_out;

    char* ws = (char*)d_ws;
    const size_t FEAT = (size_t)N_NODES * DIM * sizeof(float);       // 25.6 MB
    size_t off = 0;
    float* buf_h  = (float*)(ws + off); off += FEAT;
    float* buf_z  = (float*)(ws + off); off += FEAT;
    float* pools  = (float*)(ws + off); off += (size_t)N_GRAPHS * DIM * NLAYERS * sizeof(float);
    float* stats  = (float*)(ws + off); off += (size_t)NLAYERS * 256 * sizeof(float);
    int*   deg    = (int*)(ws + off);   off += (size_t)N_NODES * sizeof(int);      // also "cursor"
    int*   rowptr = (int*)(ws + off);   off += (size_t)(N_NODES + 1) * sizeof(int) + 12;
    int*   csr    = (int*)(ws + off);   off += (size_t)N_EDGES * sizeof(int);
    int*   gstart = (int*)(ws + off);   off += 2064;     // 513 ints, padded
    int*   bsum   = (int*)(ws + off);   off += 208;      // 49 ints, padded
    unsigned short* whi = (unsigned short*)(ws + off); off += (size_t)NLAYERS * 2 * 16384 * 2;

    hipMemsetAsync(stats, 0, (size_t)NLAYERS * 256 * sizeof(float), stream);
    hipMemsetAsync(deg, 0, (size_t)N_NODES * sizeof(int), stream);

    // ---- once per call: CSR, graph bounds, weight pre-swizzle ----
    hist_kernel<<<(N_EDGES + 255) / 256, 256, 0, stream>>>(dst, deg);
    scan1_kernel<<<49, 256, 0, stream>>>(deg, bsum);
    scan2_kernel<<<1, 64, 0, stream>>>(bsum);
    scan3_kernel<<<49, 256, 0, stream>>>(deg, bsum, rowptr, deg /*cursor*/);
    fill_kernel<<<(N_EDGES + 255) / 256, 256, 0, stream>>>(src, dst, deg, csr);
    bounds_kernel<<<(N_NODES + 255) / 256, 256, 0, stream>>>(batch, gstart);
    wconv_kernel<<<(NLAYERS * 2 * 16384 + 255) / 256, 256, 0, stream>>>(W1, W2, whi);

    for (int l = 0; l < NLAYERS; l++) {
        const float* hin = (l == 0) ? x : buf_h;
        gather_kernel<<<(N_NODES + 7) / 8, 256, 0, stream>>>(
            hin, rowptr, csr, eps + l, buf_z);
        mlp_mfma_kernel<<<(N_NODES + 63) / 64, 256, 0, stream>>>(
            buf_z,
            whi + (size_t)l * 32768,
            b1 + (size_t)l * DIM, b2 + (size_t)l * DIM,
            stats + (size_t)l * 256);
        bnpool_kernel<<<N_GRAPHS, 256, 0, stream>>>(
            buf_z, stats + (size_t)l * 256,
            gamma + (size_t)l * DIM, beta + (size_t)l * DIM,
            gstart, buf_h, pools, l);
    }
    final_kernel<<<(N_GRAPHS * NCLASSES + 255) / 256, 256, 0, stream>>>(
        pools, Wlin, blin, out);
}

// Round 7
// 501.635 us; speedup vs baseline: 1.3192x; 1.1483x over previous
//
#include <hip/hip_runtime.h>

#define N_NODES 50000
#define N_EDGES 600000
#define N_GRAPHS 512
#define DIM 128
#define NLAYERS 4
#define NCLASSES 10
#define KPD 132   // padded LDS row stride in dwords

typedef __attribute__((ext_vector_type(8))) short short8;
typedef __attribute__((ext_vector_type(4))) float f32x4;

union Frag { short8 s; uint4 u; };

// ---- fp32 <-> bf16 (RNE) helpers ----
__device__ inline unsigned short f2bf(float v) {
    union { float f; unsigned u; } c; c.f = v;
    unsigned u = c.u;
    u += 0x7FFFu + ((u >> 16) & 1u);
    return (unsigned short)(u >> 16);
}
__device__ inline float bf2f(unsigned short h) {
    union { float f; unsigned u; } c; c.u = ((unsigned)h) << 16;
    return c.f;
}
__device__ inline float bfu_lo(unsigned u) {
    union { float f; unsigned x; } c; c.x = u << 16; return c.f;
}
__device__ inline float bfu_hi(unsigned u) {
    union { float f; unsigned x; } c; c.x = u & 0xFFFF0000u; return c.f;
}
// pack 8 floats -> hi frag + lo frag (2 bf16 per dword)
__device__ inline void cvt8(const float4& x, const float4& y, uint4& hi, uint4& lo) {
    float vv[8] = {x.x, x.y, x.z, x.w, y.x, y.y, y.z, y.w};
    unsigned hh[4], ll[4];
    #pragma unroll
    for (int p = 0; p < 4; p++) {
        unsigned short h0 = f2bf(vv[2 * p]);
        unsigned short h1 = f2bf(vv[2 * p + 1]);
        unsigned short l0 = f2bf(vv[2 * p] - bf2f(h0));
        unsigned short l1 = f2bf(vv[2 * p + 1] - bf2f(h1));
        hh[p] = (unsigned)h0 | ((unsigned)h1 << 16);
        ll[p] = (unsigned)l0 | ((unsigned)l1 << 16);
    }
    hi = (uint4){hh[0], hh[1], hh[2], hh[3]};
    lo = (uint4){ll[0], ll[1], ll[2], ll[3]};
}

// ---------------------------------------------------------------------------
// CSR build
// ---------------------------------------------------------------------------
__global__ __launch_bounds__(256) void hist_kernel(
    const int* __restrict__ dst, int* __restrict__ deg)
{
    int e = blockIdx.x * 256 + threadIdx.x;
    if (e >= N_EDGES) return;
    atomicAdd(&deg[dst[e]], 1);
}

__global__ __launch_bounds__(256) void scan1_kernel(
    const int* __restrict__ deg, int* __restrict__ bsum)
{
    __shared__ int red[256];
    int t = threadIdx.x;
    int i4 = blockIdx.x * 256 + t;
    int s = 0;
    if (i4 < 12500) {
        int4 v = ((const int4*)deg)[i4];
        s = v.x + v.y + v.z + v.w;
    }
    red[t] = s;
    __syncthreads();
    for (int off = 128; off > 0; off >>= 1) {
        if (t < off) red[t] += red[t + off];
        __syncthreads();
    }
    if (t == 0) bsum[blockIdx.x] = red[0];
}

__global__ __launch_bounds__(64) void scan2_kernel(int* __restrict__ bsum)
{
    __shared__ int sh[64];
    int t = threadIdx.x;
    sh[t] = (t < 49) ? bsum[t] : 0;
    __syncthreads();
    if (t == 0) {
        int run = 0;
        for (int i = 0; i < 49; i++) { int v = sh[i]; sh[i] = run; run += v; }
    }
    __syncthreads();
    if (t < 49) bsum[t] = sh[t];
}

__global__ __launch_bounds__(256) void scan3_kernel(
    const int* __restrict__ deg, const int* __restrict__ bsum,
    int* __restrict__ rowptr, int* __restrict__ cursor)
{
    __shared__ int red[256];
    int t = threadIdx.x;
    int i4 = blockIdx.x * 256 + t;
    int4 v = {0, 0, 0, 0};
    if (i4 < 12500) v = ((const int4*)deg)[i4];
    int s = v.x + v.y + v.z + v.w;
    red[t] = s;
    __syncthreads();
    for (int off = 1; off < 256; off <<= 1) {
        int val = (t >= off) ? red[t - off] : 0;
        __syncthreads();
        red[t] += val;
        __syncthreads();
    }
    int run = bsum[blockIdx.x] + (t ? red[t - 1] : 0);
    if (i4 < 12500) {
        int4 rp;
        rp.x = run; run += v.x;
        rp.y = run; run += v.y;
        rp.z = run; run += v.z;
        rp.w = run; run += v.w;
        ((int4*)rowptr)[i4] = rp;
        ((int4*)cursor)[i4] = rp;
    }
    if (blockIdx.x == 0 && t == 0) rowptr[N_NODES] = N_EDGES;
}

__global__ __launch_bounds__(256) void fill_kernel(
    const int* __restrict__ src, const int* __restrict__ dst,
    int* __restrict__ cursor, int* __restrict__ csr)
{
    int e = blockIdx.x * 256 + threadIdx.x;
    if (e >= N_EDGES) return;
    int p = atomicAdd(&cursor[dst[e]], 1);
    csr[p] = src[e];
}

__global__ __launch_bounds__(256) void bounds_kernel(
    const int* __restrict__ batch, int* __restrict__ gstart)
{
    int n = blockIdx.x * 256 + threadIdx.x;
    if (n >= N_NODES) return;
    int b = batch[n];
    int bp = (n == 0) ? -1 : batch[n - 1];
    for (int g = bp + 1; g <= b; g++) gstart[g] = n;
    if (n == N_NODES - 1)
        for (int g = b + 1; g <= N_GRAPHS; g++) gstart[g] = N_NODES;
}

// ---------------------------------------------------------------------------
// x -> bf16 packed (2 per dword). Thread: 4 elems.
// ---------------------------------------------------------------------------
__global__ __launch_bounds__(256) void xconv_kernel(
    const float* __restrict__ x, unsigned int* __restrict__ xb)
{
    int idx = blockIdx.x * 256 + threadIdx.x;
    if (idx >= N_NODES * 32) return;
    float4 v = ((const float4*)x)[idx];
    uint2 o;
    o.x = (unsigned)f2bf(v.x) | ((unsigned)f2bf(v.y) << 16);
    o.y = (unsigned)f2bf(v.z) | ((unsigned)f2bf(v.w) << 16);
    ((uint2*)xb)[idx] = o;
}

// ---------------------------------------------------------------------------
// Pre-swizzle W1/W2 into MFMA B-fragment order, bf16 hi only.
// ---------------------------------------------------------------------------
__global__ __launch_bounds__(256) void wconv_kernel(
    const float* __restrict__ W1, const float* __restrict__ W2,
    unsigned short* __restrict__ whi)
{
    int idx = blockIdx.x * 256 + threadIdx.x;
    if (idx >= NLAYERS * 2 * 16384) return;
    int f   = idx & 16383;
    int w01 = (idx >> 14) & 1;
    int l   = idx >> 15;
    int j    = f & 7;
    int lane = (f >> 3) & 63;
    int cg   = (f >> 9) & 7;
    int ks   = f >> 12;
    int k = ks * 32 + (lane >> 4) * 8 + j;
    int n = cg * 16 + (lane & 15);
    const float* W = (w01 == 0 ? W1 : W2) + (size_t)l * 16384;
    whi[idx] = f2bf(W[k * 128 + n]);
}

// ---------------------------------------------------------------------------
// Pull-aggregation from bf16 h: z0[n] = (1+eps)*h[n] + sum h[src], fp32 accum.
// 256 threads = 8 nodes x 32 lanes; lane q: ch 4q..4q+3 (uint2 = 4 bf16).
// ---------------------------------------------------------------------------
__global__ __launch_bounds__(256) void gather_kernel(
    const unsigned int* __restrict__ hb, const int* __restrict__ rowptr,
    const int* __restrict__ csr, const float* __restrict__ epsP,
    float* __restrict__ z)
{
    int t = threadIdx.x;
    int n = blockIdx.x * 8 + (t >> 5);
    int q = t & 31;
    if (n >= N_NODES) return;
    int beg = rowptr[n], end = rowptr[n + 1];
    float e1 = 1.0f + epsP[0];
    uint2 hv = ((const uint2*)hb)[(size_t)n * 32 + q];
    float4 acc;
    acc.x = e1 * bfu_lo(hv.x); acc.y = e1 * bfu_hi(hv.x);
    acc.z = e1 * bfu_lo(hv.y); acc.w = e1 * bfu_hi(hv.y);
    int e = beg;
    for (; e + 1 < end; e += 2) {
        int s0 = csr[e], s1 = csr[e + 1];
        uint2 v0 = ((const uint2*)hb)[(size_t)s0 * 32 + q];
        uint2 v1 = ((const uint2*)hb)[(size_t)s1 * 32 + q];
        acc.x += bfu_lo(v0.x) + bfu_lo(v1.x);
        acc.y += bfu_hi(v0.x) + bfu_hi(v1.x);
        acc.z += bfu_lo(v0.y) + bfu_lo(v1.y);
        acc.w += bfu_hi(v0.y) + bfu_hi(v1.y);
    }
    if (e < end) {
        int s0 = csr[e];
        uint2 v0 = ((const uint2*)hb)[(size_t)s0 * 32 + q];
        acc.x += bfu_lo(v0.x); acc.y += bfu_hi(v0.x);
        acc.z += bfu_lo(v0.y); acc.w += bfu_hi(v0.y);
    }
    ((float4*)z)[(size_t)n * 32 + q] = acc;
}

// ---------------------------------------------------------------------------
// MFMA MLP, M=64 tile, B hi-only, A hi/lo split (unchanged from round 6)
// ---------------------------------------------------------------------------
__global__ __launch_bounds__(256, 2) void mlp_mfma_kernel(
    float* __restrict__ z,
    const unsigned short* __restrict__ whi,
    const float* __restrict__ b1, const float* __restrict__ b2,
    float* __restrict__ stats)
{
    __shared__ unsigned int tpk[64 * KPD];

    const int t = threadIdx.x;
    const int lane = t & 63;
    const int w = t >> 6;
    const int wr = w & 1, wc = w >> 1;
    const int l15 = lane & 15, quad = lane >> 4;
    const int base = blockIdx.x * 64;

    int n0 = base + 32 * wr + l15;
    int n1 = n0 + 16;
    if (n0 >= N_NODES) n0 = N_NODES - 1;
    if (n1 >= N_NODES) n1 = N_NODES - 1;
    const float* r0 = z + (size_t)n0 * 128 + quad * 8;
    const float* r1 = z + (size_t)n1 * 128 + quad * 8;

    f32x4 acc[2][4];
    #pragma unroll
    for (int s = 0; s < 2; s++)
        #pragma unroll
        for (int i = 0; i < 4; i++) acc[s][i] = (f32x4){0.f, 0.f, 0.f, 0.f};

    // ================= GEMM1 =================
    #pragma unroll
    for (int kh = 0; kh < 2; kh++) {
        Frag bf[2][4];
        float4 a0r[2][2], a1r[2][2];
        #pragma unroll
        for (int kk = 0; kk < 2; kk++) {
            int ks = kh * 2 + kk;
            #pragma unroll
            for (int i = 0; i < 4; i++) {
                size_t woff = (size_t)(((ks * 8 + wc * 4 + i) * 64 + lane) * 8);
                bf[kk][i].s = *((const short8*)&whi[woff]);
            }
            a0r[kk][0] = *((const float4*)(r0 + ks * 32));
            a0r[kk][1] = *((const float4*)(r0 + ks * 32 + 4));
            a1r[kk][0] = *((const float4*)(r1 + ks * 32));
            a1r[kk][1] = *((const float4*)(r1 + ks * 32 + 4));
        }
        #pragma unroll
        for (int kk = 0; kk < 2; kk++) {
            uint4 h0, l0, h1, l1;
            cvt8(a0r[kk][0], a0r[kk][1], h0, l0);
            cvt8(a1r[kk][0], a1r[kk][1], h1, l1);
            Frag ah0, al0, ah1, al1;
            ah0.u = h0; al0.u = l0; ah1.u = h1; al1.u = l1;
            #pragma unroll
            for (int i = 0; i < 4; i++) {
                acc[0][i] = __builtin_amdgcn_mfma_f32_16x16x32_bf16(al0.s, bf[kk][i].s, acc[0][i], 0, 0, 0);
                acc[0][i] = __builtin_amdgcn_mfma_f32_16x16x32_bf16(ah0.s, bf[kk][i].s, acc[0][i], 0, 0, 0);
                acc[1][i] = __builtin_amdgcn_mfma_f32_16x16x32_bf16(al1.s, bf[kk][i].s, acc[1][i], 0, 0, 0);
                acc[1][i] = __builtin_amdgcn_mfma_f32_16x16x32_bf16(ah1.s, bf[kk][i].s, acc[1][i], 0, 0, 0);
            }
        }
    }

    // ---- bias + relu -> packed t in LDS ----
    #pragma unroll
    for (int i = 0; i < 4; i++) {
        int col = wc * 64 + i * 16 + l15;
        float bb = b1[col];
        #pragma unroll
        for (int s = 0; s < 2; s++) {
            #pragma unroll
            for (int r = 0; r < 4; r++) {
                int m = 32 * wr + 16 * s + quad * 4 + r;
                float v = fmaxf(acc[s][i][r] + bb, 0.f);
                unsigned short h = f2bf(v);
                unsigned short lo2 = f2bf(v - bf2f(h));
                tpk[m * KPD + col] = (unsigned)h | ((unsigned)lo2 << 16);
            }
            acc[s][i] = (f32x4){0.f, 0.f, 0.f, 0.f};
        }
    }
    __syncthreads();

    // ================= GEMM2 =================
    const unsigned short* w2 = whi + 16384;
    const int arowd0 = (32 * wr + l15) * KPD;
    const int arowd1 = arowd0 + 16 * KPD;
    #pragma unroll
    for (int kh = 0; kh < 2; kh++) {
        Frag bf[2][4];
        uint4 u00[2], u01[2], u10[2], u11[2];
        #pragma unroll
        for (int kk = 0; kk < 2; kk++) {
            int ks = kh * 2 + kk;
            #pragma unroll
            for (int i = 0; i < 4; i++) {
                size_t woff = (size_t)(((ks * 8 + wc * 4 + i) * 64 + lane) * 8);
                bf[kk][i].s = *((const short8*)&w2[woff]);
            }
            int kd = ks * 32 + quad * 8;
            u00[kk] = *((uint4*)&tpk[arowd0 + kd]);
            u01[kk] = *((uint4*)&tpk[arowd0 + kd + 4]);
            u10[kk] = *((uint4*)&tpk[arowd1 + kd]);
            u11[kk] = *((uint4*)&tpk[arowd1 + kd + 4]);
        }
        #pragma unroll
        for (int kk = 0; kk < 2; kk++) {
            Frag ah0, al0, ah1, al1;
            ah0.u = (uint4){ (u00[kk].x & 0xFFFFu) | (u00[kk].y << 16),
                             (u00[kk].z & 0xFFFFu) | (u00[kk].w << 16),
                             (u01[kk].x & 0xFFFFu) | (u01[kk].y << 16),
                             (u01[kk].z & 0xFFFFu) | (u01[kk].w << 16) };
            al0.u = (uint4){ (u00[kk].x >> 16) | (u00[kk].y & 0xFFFF0000u),
                             (u00[kk].z >> 16) | (u00[kk].w & 0xFFFF0000u),
                             (u01[kk].x >> 16) | (u01[kk].y & 0xFFFF0000u),
                             (u01[kk].z >> 16) | (u01[kk].w & 0xFFFF0000u) };
            ah1.u = (uint4){ (u10[kk].x & 0xFFFFu) | (u10[kk].y << 16),
                             (u10[kk].z & 0xFFFFu) | (u10[kk].w << 16),
                             (u11[kk].x & 0xFFFFu) | (u11[kk].y << 16),
                             (u11[kk].z & 0xFFFFu) | (u11[kk].w << 16) };
            al1.u = (uint4){ (u10[kk].x >> 16) | (u10[kk].y & 0xFFFF0000u),
                             (u10[kk].z >> 16) | (u10[kk].w & 0xFFFF0000u),
                             (u11[kk].x >> 16) | (u11[kk].y & 0xFFFF0000u),
                             (u11[kk].z >> 16) | (u11[kk].w & 0xFFFF0000u) };
            #pragma unroll
            for (int i = 0; i < 4; i++) {
                acc[0][i] = __builtin_amdgcn_mfma_f32_16x16x32_bf16(al0.s, bf[kk][i].s, acc[0][i], 0, 0, 0);
                acc[0][i] = __builtin_amdgcn_mfma_f32_16x16x32_bf16(ah0.s, bf[kk][i].s, acc[0][i], 0, 0, 0);
                acc[1][i] = __builtin_amdgcn_mfma_f32_16x16x32_bf16(al1.s, bf[kk][i].s, acc[1][i], 0, 0, 0);
                acc[1][i] = __builtin_amdgcn_mfma_f32_16x16x32_bf16(ah1.s, bf[kk][i].s, acc[1][i], 0, 0, 0);
            }
        }
    }
    __syncthreads();

    // ---- bias + store z + BN partials ----
    float colsum[4], colsq[4];
    #pragma unroll
    for (int i = 0; i < 4; i++) {
        int col = wc * 64 + i * 16 + l15;
        float bb = b2[col];
        float su = 0.f, q2 = 0.f;
        #pragma unroll
        for (int s = 0; s < 2; s++) {
            #pragma unroll
            for (int r = 0; r < 4; r++) {
                int n = base + 32 * wr + 16 * s + quad * 4 + r;
                float v = acc[s][i][r] + bb;
                if (n < N_NODES) {
                    z[(size_t)n * 128 + col] = v;
                    su += v; q2 += v * v;
                }
            }
        }
        colsum[i] = su; colsq[i] = q2;
    }

    float* sums = (float*)tpk;
    float* sqs  = (float*)tpk + 1024;
    #pragma unroll
    for (int i = 0; i < 4; i++) {
        sums[(w * 4 + i) * 64 + lane] = colsum[i];
        sqs [(w * 4 + i) * 64 + lane] = colsq[i];
    }
    __syncthreads();
    if (t < 128) {
        int c = t;
        int wcc = c >> 6, ci = (c >> 4) & 3, cl = c & 15;
        float s = 0.f, q2 = 0.f;
        #pragma unroll
        for (int wrr = 0; wrr < 2; wrr++) {
            int ww = wcc * 2 + wrr;
            #pragma unroll
            for (int u = 0; u < 4; u++) {
                int ln = cl + u * 16;
                s  += sums[(ww * 4 + ci) * 64 + ln];
                q2 += sqs [(ww * 4 + ci) * 64 + ln];
            }
        }
        unsafeAtomicAdd(&stats[c], s);
        unsafeAtomicAdd(&stats[128 + c], q2);
    }
}

// ---------------------------------------------------------------------------
// BN apply + ReLU + write h (bf16) + pool: one block per graph, zero atomics
// ---------------------------------------------------------------------------
__global__ __launch_bounds__(256) void bnpool_kernel(
    const float* __restrict__ z, const float* __restrict__ stats,
    const float* __restrict__ gamma, const float* __restrict__ beta,
    const int* __restrict__ gstart, unsigned int* __restrict__ hout,
    float* __restrict__ pools, int layer)
{
    __shared__ float red[8][128];
    const int g = blockIdx.x;
    const int t = threadIdx.x;
    const int q = t & 31, r = t >> 5;
    const int beg = gstart[g], end = gstart[g + 1];

    float4 s  = ((const float4*)stats)[q];
    float4 sq = ((const float4*)stats)[32 + q];
    float4 gm = ((const float4*)gamma)[q];
    float4 bt = ((const float4*)beta)[q];
    const float invN = 1.0f / (float)N_NODES;
    float m, vr;
    float4 scl, sh;
    m = s.x * invN; vr = sq.x * invN - m * m; scl.x = gm.x * rsqrtf(vr + 1e-5f); sh.x = bt.x - m * scl.x;
    m = s.y * invN; vr = sq.y * invN - m * m; scl.y = gm.y * rsqrtf(vr + 1e-5f); sh.y = bt.y - m * scl.y;
    m = s.z * invN; vr = sq.z * invN - m * m; scl.z = gm.z * rsqrtf(vr + 1e-5f); sh.z = bt.z - m * scl.z;
    m = s.w * invN; vr = sq.w * invN - m * m; scl.w = gm.w * rsqrtf(vr + 1e-5f); sh.w = bt.w - m * scl.w;

    float4 acc = {0.f, 0.f, 0.f, 0.f};
    for (int n = beg + r; n < end; n += 8) {
        float4 zv = ((const float4*)z)[(size_t)n * 32 + q];
        float4 hv;
        hv.x = fmaxf(zv.x * scl.x + sh.x, 0.f);
        hv.y = fmaxf(zv.y * scl.y + sh.y, 0.f);
        hv.z = fmaxf(zv.z * scl.z + sh.z, 0.f);
        hv.w = fmaxf(zv.w * scl.w + sh.w, 0.f);
        uint2 p;
        p.x = (unsigned)f2bf(hv.x) | ((unsigned)f2bf(hv.y) << 16);
        p.y = (unsigned)f2bf(hv.z) | ((unsigned)f2bf(hv.w) << 16);
        ((uint2*)hout)[(size_t)n * 32 + q] = p;
        acc.x += hv.x; acc.y += hv.y; acc.z += hv.z; acc.w += hv.w;
    }
    red[r][q * 4 + 0] = acc.x;
    red[r][q * 4 + 1] = acc.y;
    red[r][q * 4 + 2] = acc.z;
    red[r][q * 4 + 3] = acc.w;
    __syncthreads();
    if (t < 128) {
        float sm = 0.f;
        #pragma unroll
        for (int rr = 0; rr < 8; rr++) sm += red[rr][t];
        pools[(size_t)g * (DIM * NLAYERS) + (size_t)layer * DIM + t] = sm;
    }
}

// ---------------------------------------------------------------------------
// Final linear head: one wave per graph, coalesced xr reads, shfl reduce.
// ---------------------------------------------------------------------------
__global__ __launch_bounds__(64) void final_kernel(
    const float* __restrict__ pools, const float* __restrict__ Wlin,
    const float* __restrict__ blin, float* __restrict__ out)
{
    int g = blockIdx.x;
    int lane = threadIdx.x;
    const float* xr = pools + (size_t)g * (DIM * NLAYERS);
    float a[NCLASSES];
    #pragma unroll
    for (int o = 0; o < NCLASSES; o++) a[o] = 0.f;
    for (int kk = 0; kk < DIM * NLAYERS; kk += 64) {
        float xv = xr[kk + lane];
        const float* wr = Wlin + (size_t)(kk + lane) * NCLASSES;
        #pragma unroll
        for (int o = 0; o < NCLASSES; o++) a[o] += xv * wr[o];
    }
    #pragma unroll
    for (int o = 0; o < NCLASSES; o++) {
        float v = a[o];
        #pragma unroll
        for (int off = 32; off > 0; off >>= 1) v += __shfl_down(v, off, 64);
        if (lane == 0) out[(size_t)g * NCLASSES + o] = v + blin[o];
    }
}

// ---------------------------------------------------------------------------
extern "C" void kernel_launch(void* const* d_in, const int* in_sizes, int n_in,
                              void* d_out, int out_size, void* d_ws, size_t ws_size,
                              hipStream_t stream)
{
    const float* x     = (const float*)d_in[0];
    const int*   src   = (const int*)d_in[1];
    const int*   dst   = ((const int*)d_in[1]) + N_EDGES;
    const int*   batch = (const int*)d_in[2];
    const float* W1    = (const float*)d_in[3];
    const float* b1    = (const float*)d_in[4];
    const float* W2    = (const float*)d_in[5];
    const float* b2    = (const float*)d_in[6];
    const float* eps   = (const float*)d_in[7];
    const float* gamma = (const float*)d_in[8];
    const float* beta  = (const float*)d_in[9];
    const float* Wlin  = (const float*)d_in[10];
    const float* blin  = (const float*)d_in[11];
    float* out = (float*)d_out;

    char* ws = (char*)d_ws;
    const size_t FEATF = (size_t)N_NODES * DIM * sizeof(float);          // 25.6 MB
    const size_t FEATH = (size_t)N_NODES * DIM * sizeof(unsigned short); // 12.8 MB
    size_t off = 0;
    unsigned int* buf_h = (unsigned int*)(ws + off); off += FEATH;       // bf16 h (also bf16 x at start)
    float* buf_z  = (float*)(ws + off); off += FEATF;
    float* pools  = (float*)(ws + off); off += (size_t)N_GRAPHS * DIM * NLAYERS * sizeof(float);
    float* stats  = (float*)(ws + off); off += (size_t)NLAYERS * 256 * sizeof(float);
    int*   deg    = (int*)(ws + off);   off += (size_t)N_NODES * sizeof(int);      // also "cursor"
    int*   rowptr = (int*)(ws + off);   off += (size_t)(N_NODES + 1) * sizeof(int) + 12;
    int*   csr    = (int*)(ws + off);   off += (size_t)N_EDGES * sizeof(int);
    int*   gstart = (int*)(ws + off);   off += 2064;
    int*   bsum   = (int*)(ws + off);   off += 208;
    unsigned short* whi = (unsigned short*)(ws + off); off += (size_t)NLAYERS * 2 * 16384 * 2;

    hipMemsetAsync(stats, 0, (size_t)NLAYERS * 256 * sizeof(float), stream);
    hipMemsetAsync(deg, 0, (size_t)N_NODES * sizeof(int), stream);

    // ---- once per call: CSR, bounds, x->bf16, weight pre-swizzle ----
    hist_kernel<<<(N_EDGES + 255) / 256, 256, 0, stream>>>(dst, deg);
    scan1_kernel<<<49, 256, 0, stream>>>(deg, bsum);
    scan2_kernel<<<1, 64, 0, stream>>>(bsum);
    scan3_kernel<<<49, 256, 0, stream>>>(deg, bsum, rowptr, deg /*cursor*/);
    fill_kernel<<<(N_EDGES + 255) / 256, 256, 0, stream>>>(src, dst, deg, csr);
    bounds_kernel<<<(N_NODES + 255) / 256, 256, 0, stream>>>(batch, gstart);
    xconv_kernel<<<(N_NODES * 32 + 255) / 256, 256, 0, stream>>>(x, buf_h);
    wconv_kernel<<<(NLAYERS * 2 * 16384 + 255) / 256, 256, 0, stream>>>(W1, W2, whi);

    for (int l = 0; l < NLAYERS; l++) {
        gather_kernel<<<(N_NODES + 7) / 8, 256, 0, stream>>>(
            buf_h, rowptr, csr, eps + l, buf_z);
        mlp_mfma_kernel<<<(N_NODES + 63) / 64, 256, 0, stream>>>(
            buf_z,
            whi + (size_t)l * 32768,
            b1 + (size_t)l * DIM, b2 + (size_t)l * DIM,
            stats + (size_t)l * 256);
        bnpool_kernel<<<N_GRAPHS, 256, 0, stream>>>(
            buf_z, stats + (size_t)l * 256,
            gamma + (size_t)l * DIM, beta + (size_t)l * DIM,
            gstart, buf_h, pools, l);
    }
    final_kernel<<<N_GRAPHS, 64, 0, stream>>>(pools, Wlin, blin, out);
}

// Round 8
// 418.748 us; speedup vs baseline: 1.5803x; 1.1979x over previous
//
#include <hip/hip_runtime.h>

#define N_NODES 50000
#define N_EDGES 600000
#define N_GRAPHS 512
#define DIM 128
#define NLAYERS 4
#define NCLASSES 10
#define KPD 132   // padded LDS row stride in dwords

typedef __attribute__((ext_vector_type(8))) short short8;
typedef __attribute__((ext_vector_type(4))) float f32x4;

union Frag { short8 s; uint4 u; };

// ---- fp32 <-> bf16 (RNE) helpers ----
__device__ inline unsigned short f2bf(float v) {
    union { float f; unsigned u; } c; c.f = v;
    unsigned u = c.u;
    u += 0x7FFFu + ((u >> 16) & 1u);
    return (unsigned short)(u >> 16);
}
__device__ inline float bf2f(unsigned short h) {
    union { float f; unsigned u; } c; c.u = ((unsigned)h) << 16;
    return c.f;
}
__device__ inline float bfu_lo(unsigned u) {
    union { float f; unsigned x; } c; c.x = u << 16; return c.f;
}
__device__ inline float bfu_hi(unsigned u) {
    union { float f; unsigned x; } c; c.x = u & 0xFFFF0000u; return c.f;
}
// add a 16B chunk (8 packed bf16) into 8 fp32 accumulators
__device__ inline void addRow(float* acc, const uint4& v) {
    acc[0] += bfu_lo(v.x); acc[1] += bfu_hi(v.x);
    acc[2] += bfu_lo(v.y); acc[3] += bfu_hi(v.y);
    acc[4] += bfu_lo(v.z); acc[5] += bfu_hi(v.z);
    acc[6] += bfu_lo(v.w); acc[7] += bfu_hi(v.w);
}

// ---------------------------------------------------------------------------
// CSR build
// ---------------------------------------------------------------------------
__global__ __launch_bounds__(256) void hist_kernel(
    const int* __restrict__ dst, int* __restrict__ deg)
{
    int e = blockIdx.x * 256 + threadIdx.x;
    if (e >= N_EDGES) return;
    atomicAdd(&deg[dst[e]], 1);
}

__global__ __launch_bounds__(256) void scan1_kernel(
    const int* __restrict__ deg, int* __restrict__ bsum)
{
    __shared__ int red[256];
    int t = threadIdx.x;
    int i4 = blockIdx.x * 256 + t;
    int s = 0;
    if (i4 < 12500) {
        int4 v = ((const int4*)deg)[i4];
        s = v.x + v.y + v.z + v.w;
    }
    red[t] = s;
    __syncthreads();
    for (int off = 128; off > 0; off >>= 1) {
        if (t < off) red[t] += red[t + off];
        __syncthreads();
    }
    if (t == 0) bsum[blockIdx.x] = red[0];
}

__global__ __launch_bounds__(64) void scan2_kernel(int* __restrict__ bsum)
{
    __shared__ int sh[64];
    int t = threadIdx.x;
    sh[t] = (t < 49) ? bsum[t] : 0;
    __syncthreads();
    if (t == 0) {
        int run = 0;
        for (int i = 0; i < 49; i++) { int v = sh[i]; sh[i] = run; run += v; }
    }
    __syncthreads();
    if (t < 49) bsum[t] = sh[t];
}

__global__ __launch_bounds__(256) void scan3_kernel(
    const int* __restrict__ deg, const int* __restrict__ bsum,
    int* __restrict__ rowptr, int* __restrict__ cursor)
{
    __shared__ int red[256];
    int t = threadIdx.x;
    int i4 = blockIdx.x * 256 + t;
    int4 v = {0, 0, 0, 0};
    if (i4 < 12500) v = ((const int4*)deg)[i4];
    int s = v.x + v.y + v.z + v.w;
    red[t] = s;
    __syncthreads();
    for (int off = 1; off < 256; off <<= 1) {
        int val = (t >= off) ? red[t - off] : 0;
        __syncthreads();
        red[t] += val;
        __syncthreads();
    }
    int run = bsum[blockIdx.x] + (t ? red[t - 1] : 0);
    if (i4 < 12500) {
        int4 rp;
        rp.x = run; run += v.x;
        rp.y = run; run += v.y;
        rp.z = run; run += v.z;
        rp.w = run; run += v.w;
        ((int4*)rowptr)[i4] = rp;
        ((int4*)cursor)[i4] = rp;
    }
    if (blockIdx.x == 0 && t == 0) rowptr[N_NODES] = N_EDGES;
}

__global__ __launch_bounds__(256) void fill_kernel(
    const int* __restrict__ src, const int* __restrict__ dst,
    int* __restrict__ cursor, int* __restrict__ csr)
{
    int e = blockIdx.x * 256 + threadIdx.x;
    if (e >= N_EDGES) return;
    int p = atomicAdd(&cursor[dst[e]], 1);
    csr[p] = src[e];
}

__global__ __launch_bounds__(256) void bounds_kernel(
    const int* __restrict__ batch, int* __restrict__ gstart)
{
    int n = blockIdx.x * 256 + threadIdx.x;
    if (n >= N_NODES) return;
    int b = batch[n];
    int bp = (n == 0) ? -1 : batch[n - 1];
    for (int g = bp + 1; g <= b; g++) gstart[g] = n;
    if (n == N_NODES - 1)
        for (int g = b + 1; g <= N_GRAPHS; g++) gstart[g] = N_NODES;
}

// ---------------------------------------------------------------------------
// x -> bf16 packed (2 per dword)
// ---------------------------------------------------------------------------
__global__ __launch_bounds__(256) void xconv_kernel(
    const float* __restrict__ x, unsigned int* __restrict__ xb)
{
    int idx = blockIdx.x * 256 + threadIdx.x;
    if (idx >= N_NODES * 32) return;
    float4 v = ((const float4*)x)[idx];
    uint2 o;
    o.x = (unsigned)f2bf(v.x) | ((unsigned)f2bf(v.y) << 16);
    o.y = (unsigned)f2bf(v.z) | ((unsigned)f2bf(v.w) << 16);
    ((uint2*)xb)[idx] = o;
}

// ---------------------------------------------------------------------------
// Pre-swizzle W1/W2 into MFMA B-fragment order, bf16 hi only.
// ---------------------------------------------------------------------------
__global__ __launch_bounds__(256) void wconv_kernel(
    const float* __restrict__ W1, const float* __restrict__ W2,
    unsigned short* __restrict__ whi)
{
    int idx = blockIdx.x * 256 + threadIdx.x;
    if (idx >= NLAYERS * 2 * 16384) return;
    int f   = idx & 16383;
    int w01 = (idx >> 14) & 1;
    int l   = idx >> 15;
    int j    = f & 7;
    int lane = (f >> 3) & 63;
    int cg   = (f >> 9) & 7;
    int ks   = f >> 12;
    int k = ks * 32 + (lane >> 4) * 8 + j;
    int n = cg * 16 + (lane & 15);
    const float* W = (w01 == 0 ? W1 : W2) + (size_t)l * 16384;
    whi[idx] = f2bf(W[k * 128 + n]);
}

// ---------------------------------------------------------------------------
// FUSED GIN layer: pull-gather (bf16 h) -> LDS -> GEMM1 -> relu -> GEMM2
//   z = relu( ((1+eps)h + sum_nb h) @ W1 + b1 ) @ W2 + b2    + BN stats
// Block = 64 nodes, 256 threads.
// Phase A: thread (m=t>>2, c=t&3) aggregates node base+m, channels c*32..+31
//          in fp32 regs, packs (hi|lo<<16) dwords into tpk[m][k].
// GEMM phases: 4 waves; wr=w&1 -> rows 32wr (2 strips), wc=w>>1 -> cols 64wc.
// ---------------------------------------------------------------------------
__global__ __launch_bounds__(256, 2) void gin_layer_kernel(
    const unsigned int* __restrict__ hb,
    const int* __restrict__ rowptr, const int* __restrict__ csr,
    const float* __restrict__ epsP,
    float* __restrict__ z,
    const unsigned short* __restrict__ whi,
    const float* __restrict__ b1, const float* __restrict__ b2,
    float* __restrict__ stats)
{
    __shared__ unsigned int tpk[64 * KPD];   // 33792 B

    const int t = threadIdx.x;
    const int lane = t & 63;
    const int w = t >> 6;
    const int wr = w & 1, wc = w >> 1;
    const int l15 = lane & 15, quad = lane >> 4;
    const int base = blockIdx.x * 64;

    // ---------------- Phase A: fused pull-aggregation ----------------
    {
        const int m = t >> 2;
        const int c = t & 3;
        const int n = base + m;
        const uint4* hb4 = (const uint4*)hb;
        float acc[32];
        #pragma unroll
        for (int i = 0; i < 32; i++) acc[i] = 0.f;
        if (n < N_NODES) {
            const float e1 = 1.0f + epsP[0];
            const uint4* self = hb4 + (size_t)n * 16 + c * 4;
            #pragma unroll
            for (int j = 0; j < 4; j++) {
                uint4 v = self[j];
                float* a = acc + j * 8;
                a[0] = e1 * bfu_lo(v.x); a[1] = e1 * bfu_hi(v.x);
                a[2] = e1 * bfu_lo(v.y); a[3] = e1 * bfu_hi(v.y);
                a[4] = e1 * bfu_lo(v.z); a[5] = e1 * bfu_hi(v.z);
                a[6] = e1 * bfu_lo(v.w); a[7] = e1 * bfu_hi(v.w);
            }
            int beg = rowptr[n], end = rowptr[n + 1];
            int e = beg;
            for (; e + 1 < end; e += 2) {
                int s0 = csr[e], s1 = csr[e + 1];
                const uint4* r0 = hb4 + (size_t)s0 * 16 + c * 4;
                const uint4* r1 = hb4 + (size_t)s1 * 16 + c * 4;
                uint4 a0 = r0[0], a1 = r0[1], a2 = r0[2], a3 = r0[3];
                uint4 b0 = r1[0], b1v = r1[1], b2v = r1[2], b3 = r1[3];
                addRow(acc + 0, a0);  addRow(acc + 8, a1);
                addRow(acc + 16, a2); addRow(acc + 24, a3);
                addRow(acc + 0, b0);  addRow(acc + 8, b1v);
                addRow(acc + 16, b2v); addRow(acc + 24, b3);
            }
            if (e < end) {
                int s0 = csr[e];
                const uint4* r0 = hb4 + (size_t)s0 * 16 + c * 4;
                uint4 a0 = r0[0], a1 = r0[1], a2 = r0[2], a3 = r0[3];
                addRow(acc + 0, a0);  addRow(acc + 8, a1);
                addRow(acc + 16, a2); addRow(acc + 24, a3);
            }
        }
        unsigned int* dp = &tpk[m * KPD + c * 32];
        #pragma unroll
        for (int i = 0; i < 32; i++) {
            unsigned short h = f2bf(acc[i]);
            unsigned short lo = f2bf(acc[i] - bf2f(h));
            dp[i] = (unsigned)h | ((unsigned)lo << 16);
        }
    }
    __syncthreads();

    f32x4 acc[2][4];
    #pragma unroll
    for (int s = 0; s < 2; s++)
        #pragma unroll
        for (int i = 0; i < 4; i++) acc[s][i] = (f32x4){0.f, 0.f, 0.f, 0.f};

    const int arowd0 = (32 * wr + l15) * KPD;
    const int arowd1 = arowd0 + 16 * KPD;

    // ================= GEMM1: z0 @ W1 (A from LDS) =================
    #pragma unroll
    for (int kh = 0; kh < 2; kh++) {
        Frag bf[2][4];
        uint4 u00[2], u01[2], u10[2], u11[2];
        #pragma unroll
        for (int kk = 0; kk < 2; kk++) {
            int ks = kh * 2 + kk;
            #pragma unroll
            for (int i = 0; i < 4; i++) {
                size_t woff = (size_t)(((ks * 8 + wc * 4 + i) * 64 + lane) * 8);
                bf[kk][i].s = *((const short8*)&whi[woff]);
            }
            int kd = ks * 32 + quad * 8;
            u00[kk] = *((uint4*)&tpk[arowd0 + kd]);
            u01[kk] = *((uint4*)&tpk[arowd0 + kd + 4]);
            u10[kk] = *((uint4*)&tpk[arowd1 + kd]);
            u11[kk] = *((uint4*)&tpk[arowd1 + kd + 4]);
        }
        #pragma unroll
        for (int kk = 0; kk < 2; kk++) {
            Frag ah0, al0, ah1, al1;
            ah0.u = (uint4){ (u00[kk].x & 0xFFFFu) | (u00[kk].y << 16),
                             (u00[kk].z & 0xFFFFu) | (u00[kk].w << 16),
                             (u01[kk].x & 0xFFFFu) | (u01[kk].y << 16),
                             (u01[kk].z & 0xFFFFu) | (u01[kk].w << 16) };
            al0.u = (uint4){ (u00[kk].x >> 16) | (u00[kk].y & 0xFFFF0000u),
                             (u00[kk].z >> 16) | (u00[kk].w & 0xFFFF0000u),
                             (u01[kk].x >> 16) | (u01[kk].y & 0xFFFF0000u),
                             (u01[kk].z >> 16) | (u01[kk].w & 0xFFFF0000u) };
            ah1.u = (uint4){ (u10[kk].x & 0xFFFFu) | (u10[kk].y << 16),
                             (u10[kk].z & 0xFFFFu) | (u10[kk].w << 16),
                             (u11[kk].x & 0xFFFFu) | (u11[kk].y << 16),
                             (u11[kk].z & 0xFFFFu) | (u11[kk].w << 16) };
            al1.u = (uint4){ (u10[kk].x >> 16) | (u10[kk].y & 0xFFFF0000u),
                             (u10[kk].z >> 16) | (u10[kk].w & 0xFFFF0000u),
                             (u11[kk].x >> 16) | (u11[kk].y & 0xFFFF0000u),
                             (u11[kk].z >> 16) | (u11[kk].w & 0xFFFF0000u) };
            #pragma unroll
            for (int i = 0; i < 4; i++) {
                acc[0][i] = __builtin_amdgcn_mfma_f32_16x16x32_bf16(al0.s, bf[kk][i].s, acc[0][i], 0, 0, 0);
                acc[0][i] = __builtin_amdgcn_mfma_f32_16x16x32_bf16(ah0.s, bf[kk][i].s, acc[0][i], 0, 0, 0);
                acc[1][i] = __builtin_amdgcn_mfma_f32_16x16x32_bf16(al1.s, bf[kk][i].s, acc[1][i], 0, 0, 0);
                acc[1][i] = __builtin_amdgcn_mfma_f32_16x16x32_bf16(ah1.s, bf[kk][i].s, acc[1][i], 0, 0, 0);
            }
        }
    }
    __syncthreads();   // all z0 reads from tpk complete before t overwrites it

    // ---- bias + relu -> packed t in LDS ----
    #pragma unroll
    for (int i = 0; i < 4; i++) {
        int col = wc * 64 + i * 16 + l15;
        float bb = b1[col];
        #pragma unroll
        for (int s = 0; s < 2; s++) {
            #pragma unroll
            for (int r = 0; r < 4; r++) {
                int m = 32 * wr + 16 * s + quad * 4 + r;
                float v = fmaxf(acc[s][i][r] + bb, 0.f);
                unsigned short h = f2bf(v);
                unsigned short lo2 = f2bf(v - bf2f(h));
                tpk[m * KPD + col] = (unsigned)h | ((unsigned)lo2 << 16);
            }
            acc[s][i] = (f32x4){0.f, 0.f, 0.f, 0.f};
        }
    }
    __syncthreads();

    // ================= GEMM2: t @ W2 =================
    const unsigned short* w2 = whi + 16384;
    #pragma unroll
    for (int kh = 0; kh < 2; kh++) {
        Frag bf[2][4];
        uint4 u00[2], u01[2], u10[2], u11[2];
        #pragma unroll
        for (int kk = 0; kk < 2; kk++) {
            int ks = kh * 2 + kk;
            #pragma unroll
            for (int i = 0; i < 4; i++) {
                size_t woff = (size_t)(((ks * 8 + wc * 4 + i) * 64 + lane) * 8);
                bf[kk][i].s = *((const short8*)&w2[woff]);
            }
            int kd = ks * 32 + quad * 8;
            u00[kk] = *((uint4*)&tpk[arowd0 + kd]);
            u01[kk] = *((uint4*)&tpk[arowd0 + kd + 4]);
            u10[kk] = *((uint4*)&tpk[arowd1 + kd]);
            u11[kk] = *((uint4*)&tpk[arowd1 + kd + 4]);
        }
        #pragma unroll
        for (int kk = 0; kk < 2; kk++) {
            Frag ah0, al0, ah1, al1;
            ah0.u = (uint4){ (u00[kk].x & 0xFFFFu) | (u00[kk].y << 16),
                             (u00[kk].z & 0xFFFFu) | (u00[kk].w << 16),
                             (u01[kk].x & 0xFFFFu) | (u01[kk].y << 16),
                             (u01[kk].z & 0xFFFFu) | (u01[kk].w << 16) };
            al0.u = (uint4){ (u00[kk].x >> 16) | (u00[kk].y & 0xFFFF0000u),
                             (u00[kk].z >> 16) | (u00[kk].w & 0xFFFF0000u),
                             (u01[kk].x >> 16) | (u01[kk].y & 0xFFFF0000u),
                             (u01[kk].z >> 16) | (u01[kk].w & 0xFFFF0000u) };
            ah1.u = (uint4){ (u10[kk].x & 0xFFFFu) | (u10[kk].y << 16),
                             (u10[kk].z & 0xFFFFu) | (u10[kk].w << 16),
                             (u11[kk].x & 0xFFFFu) | (u11[kk].y << 16),
                             (u11[kk].z & 0xFFFFu) | (u11[kk].w << 16) };
            al1.u = (uint4){ (u10[kk].x >> 16) | (u10[kk].y & 0xFFFF0000u),
                             (u10[kk].z >> 16) | (u10[kk].w & 0xFFFF0000u),
                             (u11[kk].x >> 16) | (u11[kk].y & 0xFFFF0000u),
                             (u11[kk].z >> 16) | (u11[kk].w & 0xFFFF0000u) };
            #pragma unroll
            for (int i = 0; i < 4; i++) {
                acc[0][i] = __builtin_amdgcn_mfma_f32_16x16x32_bf16(al0.s, bf[kk][i].s, acc[0][i], 0, 0, 0);
                acc[0][i] = __builtin_amdgcn_mfma_f32_16x16x32_bf16(ah0.s, bf[kk][i].s, acc[0][i], 0, 0, 0);
                acc[1][i] = __builtin_amdgcn_mfma_f32_16x16x32_bf16(al1.s, bf[kk][i].s, acc[1][i], 0, 0, 0);
                acc[1][i] = __builtin_amdgcn_mfma_f32_16x16x32_bf16(ah1.s, bf[kk][i].s, acc[1][i], 0, 0, 0);
            }
        }
    }
    __syncthreads();

    // ---- bias + store z + BN partials ----
    float colsum[4], colsq[4];
    #pragma unroll
    for (int i = 0; i < 4; i++) {
        int col = wc * 64 + i * 16 + l15;
        float bb = b2[col];
        float su = 0.f, q2 = 0.f;
        #pragma unroll
        for (int s = 0; s < 2; s++) {
            #pragma unroll
            for (int r = 0; r < 4; r++) {
                int n = base + 32 * wr + 16 * s + quad * 4 + r;
                float v = acc[s][i][r] + bb;
                if (n < N_NODES) {
                    z[(size_t)n * 128 + col] = v;
                    su += v; q2 += v * v;
                }
            }
        }
        colsum[i] = su; colsq[i] = q2;
    }

    float* sums = (float*)tpk;
    float* sqs  = (float*)tpk + 1024;
    #pragma unroll
    for (int i = 0; i < 4; i++) {
        sums[(w * 4 + i) * 64 + lane] = colsum[i];
        sqs [(w * 4 + i) * 64 + lane] = colsq[i];
    }
    __syncthreads();
    if (t < 128) {
        int c = t;
        int wcc = c >> 6, ci = (c >> 4) & 3, cl = c & 15;
        float s = 0.f, q2 = 0.f;
        #pragma unroll
        for (int wrr = 0; wrr < 2; wrr++) {
            int ww = wcc * 2 + wrr;
            #pragma unroll
            for (int u = 0; u < 4; u++) {
                int ln = cl + u * 16;
                s  += sums[(ww * 4 + ci) * 64 + ln];
                q2 += sqs [(ww * 4 + ci) * 64 + ln];
            }
        }
        unsafeAtomicAdd(&stats[c], s);
        unsafeAtomicAdd(&stats[128 + c], q2);
    }
}

// ---------------------------------------------------------------------------
// BN apply + ReLU + write h (bf16) + pool: one block per graph, zero atomics
// ---------------------------------------------------------------------------
__global__ __launch_bounds__(256) void bnpool_kernel(
    const float* __restrict__ z, const float* __restrict__ stats,
    const float* __restrict__ gamma, const float* __restrict__ beta,
    const int* __restrict__ gstart, unsigned int* __restrict__ hout,
    float* __restrict__ pools, int layer)
{
    __shared__ float red[8][128];
    const int g = blockIdx.x;
    const int t = threadIdx.x;
    const int q = t & 31, r = t >> 5;
    const int beg = gstart[g], end = gstart[g + 1];

    float4 s  = ((const float4*)stats)[q];
    float4 sq = ((const float4*)stats)[32 + q];
    float4 gm = ((const float4*)gamma)[q];
    float4 bt = ((const float4*)beta)[q];
    const float invN = 1.0f / (float)N_NODES;
    float m, vr;
    float4 scl, sh;
    m = s.x * invN; vr = sq.x * invN - m * m; scl.x = gm.x * rsqrtf(vr + 1e-5f); sh.x = bt.x - m * scl.x;
    m = s.y * invN; vr = sq.y * invN - m * m; scl.y = gm.y * rsqrtf(vr + 1e-5f); sh.y = bt.y - m * scl.y;
    m = s.z * invN; vr = sq.z * invN - m * m; scl.z = gm.z * rsqrtf(vr + 1e-5f); sh.z = bt.z - m * scl.z;
    m = s.w * invN; vr = sq.w * invN - m * m; scl.w = gm.w * rsqrtf(vr + 1e-5f); sh.w = bt.w - m * scl.w;

    float4 acc = {0.f, 0.f, 0.f, 0.f};
    for (int n = beg + r; n < end; n += 8) {
        float4 zv = ((const float4*)z)[(size_t)n * 32 + q];
        float4 hv;
        hv.x = fmaxf(zv.x * scl.x + sh.x, 0.f);
        hv.y = fmaxf(zv.y * scl.y + sh.y, 0.f);
        hv.z = fmaxf(zv.z * scl.z + sh.z, 0.f);
        hv.w = fmaxf(zv.w * scl.w + sh.w, 0.f);
        uint2 p;
        p.x = (unsigned)f2bf(hv.x) | ((unsigned)f2bf(hv.y) << 16);
        p.y = (unsigned)f2bf(hv.z) | ((unsigned)f2bf(hv.w) << 16);
        ((uint2*)hout)[(size_t)n * 32 + q] = p;
        acc.x += hv.x; acc.y += hv.y; acc.z += hv.z; acc.w += hv.w;
    }
    red[r][q * 4 + 0] = acc.x;
    red[r][q * 4 + 1] = acc.y;
    red[r][q * 4 + 2] = acc.z;
    red[r][q * 4 + 3] = acc.w;
    __syncthreads();
    if (t < 128) {
        float sm = 0.f;
        #pragma unroll
        for (int rr = 0; rr < 8; rr++) sm += red[rr][t];
        pools[(size_t)g * (DIM * NLAYERS) + (size_t)layer * DIM + t] = sm;
    }
}

// ---------------------------------------------------------------------------
// Final linear head: one wave per graph
// ---------------------------------------------------------------------------
__global__ __launch_bounds__(64) void final_kernel(
    const float* __restrict__ pools, const float* __restrict__ Wlin,
    const float* __restrict__ blin, float* __restrict__ out)
{
    int g = blockIdx.x;
    int lane = threadIdx.x;
    const float* xr = pools + (size_t)g * (DIM * NLAYERS);
    float a[NCLASSES];
    #pragma unroll
    for (int o = 0; o < NCLASSES; o++) a[o] = 0.f;
    for (int kk = 0; kk < DIM * NLAYERS; kk += 64) {
        float xv = xr[kk + lane];
        const float* wr = Wlin + (size_t)(kk + lane) * NCLASSES;
        #pragma unroll
        for (int o = 0; o < NCLASSES; o++) a[o] += xv * wr[o];
    }
    #pragma unroll
    for (int o = 0; o < NCLASSES; o++) {
        float v = a[o];
        #pragma unroll
        for (int off = 32; off > 0; off >>= 1) v += __shfl_down(v, off, 64);
        if (lane == 0) out[(size_t)g * NCLASSES + o] = v + blin[o];
    }
}

// ---------------------------------------------------------------------------
extern "C" void kernel_launch(void* const* d_in, const int* in_sizes, int n_in,
                              void* d_out, int out_size, void* d_ws, size_t ws_size,
                              hipStream_t stream)
{
    const float* x     = (const float*)d_in[0];
    const int*   src   = (const int*)d_in[1];
    const int*   dst   = ((const int*)d_in[1]) + N_EDGES;
    const int*   batch = (const int*)d_in[2];
    const float* W1    = (const float*)d_in[3];
    const float* b1    = (const float*)d_in[4];
    const float* W2    = (const float*)d_in[5];
    const float* b2    = (const float*)d_in[6];
    const float* eps   = (const float*)d_in[7];
    const float* gamma = (const float*)d_in[8];
    const float* beta  = (const float*)d_in[9];
    const float* Wlin  = (const float*)d_in[10];
    const float* blin  = (const float*)d_in[11];
    float* out = (float*)d_out;

    char* ws = (char*)d_ws;
    const size_t FEATF = (size_t)N_NODES * DIM * sizeof(float);          // 25.6 MB
    const size_t FEATH = (size_t)N_NODES * DIM * sizeof(unsigned short); // 12.8 MB
    size_t off = 0;
    unsigned int* buf_h = (unsigned int*)(ws + off); off += FEATH;       // bf16 h
    float* buf_z  = (float*)(ws + off); off += FEATF;                    // fp32 z (MLP out)
    float* pools  = (float*)(ws + off); off += (size_t)N_GRAPHS * DIM * NLAYERS * sizeof(float);
    float* stats  = (float*)(ws + off); off += (size_t)NLAYERS * 256 * sizeof(float);
    int*   deg    = (int*)(ws + off);   off += (size_t)N_NODES * sizeof(int);      // also "cursor"
    int*   rowptr = (int*)(ws + off);   off += (size_t)(N_NODES + 1) * sizeof(int) + 12;
    int*   csr    = (int*)(ws + off);   off += (size_t)N_EDGES * sizeof(int);
    int*   gstart = (int*)(ws + off);   off += 2064;
    int*   bsum   = (int*)(ws + off);   off += 208;
    unsigned short* whi = (unsigned short*)(ws + off); off += (size_t)NLAYERS * 2 * 16384 * 2;

    hipMemsetAsync(stats, 0, (size_t)NLAYERS * 256 * sizeof(float), stream);
    hipMemsetAsync(deg, 0, (size_t)N_NODES * sizeof(int), stream);

    // ---- once per call: CSR, bounds, x->bf16, weight pre-swizzle ----
    hist_kernel<<<(N_EDGES + 255) / 256, 256, 0, stream>>>(dst, deg);
    scan1_kernel<<<49, 256, 0, stream>>>(deg, bsum);
    scan2_kernel<<<1, 64, 0, stream>>>(bsum);
    scan3_kernel<<<49, 256, 0, stream>>>(deg, bsum, rowptr, deg /*cursor*/);
    fill_kernel<<<(N_EDGES + 255) / 256, 256, 0, stream>>>(src, dst, deg, csr);
    bounds_kernel<<<(N_NODES + 255) / 256, 256, 0, stream>>>(batch, gstart);
    xconv_kernel<<<(N_NODES * 32 + 255) / 256, 256, 0, stream>>>(x, buf_h);
    wconv_kernel<<<(NLAYERS * 2 * 16384 + 255) / 256, 256, 0, stream>>>(W1, W2, whi);

    for (int l = 0; l < NLAYERS; l++) {
        gin_layer_kernel<<<(N_NODES + 63) / 64, 256, 0, stream>>>(
            buf_h, rowptr, csr, eps + l, buf_z,
            whi + (size_t)l * 32768,
            b1 + (size_t)l * DIM, b2 + (size_t)l * DIM,
            stats + (size_t)l * 256);
        bnpool_kernel<<<N_GRAPHS, 256, 0, stream>>>(
            buf_z, stats + (size_t)l * 256,
            gamma + (size_t)l * DIM, beta + (size_t)l * DIM,
            gstart, buf_h, pools, l);
    }
    final_kernel<<<N_GRAPHS, 64, 0, stream>>>(pools, Wlin, blin, out);
}